// Round 1
// baseline (2106.608 us; speedup 1.0000x reference)
//
#include <hip/hip_runtime.h>

#define BP 8
#define WIMG 1216
#define HIMG 352

__device__ __forceinline__ float relu_(float x){ return fmaxf(x, 0.f); }
__device__ __forceinline__ float sigmoid_(float x){ return 1.f/(1.f+__expf(-x)); }
__device__ __forceinline__ float softplus_(float x){
  return fmaxf(x,0.f) + log1pf(__expf(-fabsf(x)));
}

// ---------------- transpose bev (z,c,x,y) -> vf (z,x,y,c) ----------------
__global__ void k_transpose(const float* __restrict__ src, float* __restrict__ dst){
  __shared__ float tile[32][33];
  int zx = blockIdx.z;              // z*128 + x
  int y0 = blockIdx.x * 32;
  int c0 = blockIdx.y * 32;
  int z = zx >> 7, x = zx & 127;
  const float* s = src + (size_t)z*2097152 + (size_t)x*128;
  for (int i = threadIdx.y; i < 32; i += 8)
    tile[i][threadIdx.x] = s[(size_t)(c0+i)*16384 + (size_t)(y0 + threadIdx.x)];
  __syncthreads();
  float* d = dst + ((size_t)zx*128 + y0)*128 + c0;
  for (int i = threadIdx.y; i < 32; i += 8)
    d[(size_t)i*128 + threadIdx.x] = tile[threadIdx.x][i];
}

// ---------------- per-ray unit dirs + viewdirs ----------------
__global__ void k_rayinit(const float* __restrict__ camK, const int* __restrict__ pix,
                          const float* __restrict__ Tsi,
                          float* __restrict__ unit, float* __restrict__ viewdir, int R){
  int r = blockIdx.x*blockDim.x + threadIdx.x;
  if (r >= R) return;
  float a=camK[0],b=camK[1],c=camK[2],d=camK[3],e=camK[4],f=camK[5],g=camK[6],h=camK[7],i=camK[8];
  float c00 = e*i-f*h, c01 = c*h-b*i, c02 = b*f-c*e;
  float c10 = f*g-d*i, c11 = a*i-c*g, c12 = c*d-a*f;
  float c20 = d*h-e*g, c21 = b*g-a*h, c22 = a*e-b*d;
  float det = a*c00 + b*c10 + c*c20;
  float id = 1.f/det;
  float u = (float)pix[2*r], v = (float)pix[2*r+1];
  float dx = (c00*u + c01*v + c02)*id;
  float dy = (c10*u + c11*v + c12)*id;
  float dz = (c20*u + c21*v + c22)*id;
  float n = sqrtf(dx*dx+dy*dy+dz*dz);
  dx/=n; dy/=n; dz/=n;
  unit[3*r]=dx; unit[3*r+1]=dy; unit[3*r+2]=dz;
  viewdir[3*r]   = Tsi[0]*dx + Tsi[1]*dy + Tsi[2]*dz;
  viewdir[3*r+1] = Tsi[4]*dx + Tsi[5]*dy + Tsi[6]*dz;
  viewdir[3*r+2] = Tsi[8]*dx + Tsi[9]*dy + Tsi[10]*dz;
}

// ---------------- trilinear ----------------
struct Tri { int x0,y0,z0; float fx,fy,fz,scale; };

__device__ __forceinline__ Tri tri_setup(float px, float py, float pz){
  Tri t;
  float gx = (px + 25.6f) / 0.4f;
  float gy = (py + 25.6f) / 0.4f;
  float gz = (pz + 2.0f)  / 0.4f;
  bool inb = (gx>=0.f)&&(gx<=127.f)&&(gy>=0.f)&&(gy<=127.f)&&(gz>=0.f)&&(gz<=15.f);
  gx = fminf(fmaxf(gx,0.f),127.f);
  gy = fminf(fmaxf(gy,0.f),127.f);
  gz = fminf(fmaxf(gz,0.f),15.f);
  int x0 = min(max((int)floorf(gx),0),126);
  int y0 = min(max((int)floorf(gy),0),126);
  int z0 = min(max((int)floorf(gz),0),14);
  t.x0=x0; t.y0=y0; t.z0=z0;
  t.fx = gx-(float)x0; t.fy = gy-(float)y0; t.fz = gz-(float)z0;
  t.scale = inb ? 1.f : 0.f;
  return t;
}

__device__ __forceinline__ float tri_gather(const float* __restrict__ vf, int mode, int c, const Tri& t){
  float acc = 0.f;
  #pragma unroll
  for (int dz=0; dz<2; ++dz)
  #pragma unroll
  for (int dx=0; dx<2; ++dx)
  #pragma unroll
  for (int dy=0; dy<2; ++dy) {
    float w = (dz? t.fz : 1.f-t.fz) * (dx? t.fx : 1.f-t.fx) * (dy? t.fy : 1.f-t.fy);
    int z = t.z0+dz, x = t.x0+dx, y = t.y0+dy;
    int addr = mode ? (((z*128 + x)*128 + y)*128 + c)
                    : (z*2097152 + c*16384 + x*128 + y);
    acc = fmaf(w, vf[addr], acc);
  }
  return acc * t.scale;
}

__device__ __forceinline__ void point_world(float ux,float uy,float uz,float t,
                                            const float* __restrict__ Tsi,
                                            float& px,float& py,float& pz){
  float wx=ux*t, wy=uy*t, wz=uz*t;
  px = Tsi[0]*wx + Tsi[1]*wy + Tsi[2]*wz + Tsi[3];
  py = Tsi[4]*wx + Tsi[5]*wy + Tsi[6]*wz + Tsi[7];
  pz = Tsi[8]*wx + Tsi[9]*wy + Tsi[10]*wz + Tsi[11];
}

// 128-deep MAC: acc[p] += sum_k src[p][k] * W[k*128 + tid-col]
__device__ __forceinline__ void mac128(const float (*src)[128], const float* __restrict__ Wcol,
                                       float* acc){
  for (int k4 = 0; k4 < 32; ++k4) {
    float w0 = Wcol[(k4*4+0)*128];
    float w1 = Wcol[(k4*4+1)*128];
    float w2 = Wcol[(k4*4+2)*128];
    float w3 = Wcol[(k4*4+3)*128];
    #pragma unroll
    for (int p = 0; p < BP; ++p) {
      float4 h4 = *(const float4*)(&src[p][k4*4]);
      acc[p] = fmaf(h4.x, w0, acc[p]);
      acc[p] = fmaf(h4.y, w1, acc[p]);
      acc[p] = fmaf(h4.z, w2, acc[p]);
      acc[p] = fmaf(h4.w, w3, acc[p]);
    }
  }
}

// ---------------- fused trilinear + PE + resnet_fc ----------------
// OUTD=2: gaussian pass (writes means/stds); OUTD=4: main pass (writes outbuf)
template<int OUTD, int RAY_SHIFT>
__global__ __launch_bounds__(128) void k_mlp(
    const float* __restrict__ vf, int mode,
    const float* __restrict__ unit, const float* __restrict__ viewdir,
    const float* __restrict__ Tsi,
    const float* __restrict__ dvals,
    const float* __restrict__ w_in, const float* __restrict__ b_in,
    const float* __restrict__ wz,  const float* __restrict__ bz,
    const float* __restrict__ w0,  const float* __restrict__ b0,
    const float* __restrict__ w1,  const float* __restrict__ b1,
    const float* __restrict__ w_out, const float* __restrict__ b_out,
    float* __restrict__ means, float* __restrict__ stds,
    float* __restrict__ outbuf)
{
  __shared__ __align__(16) float zf[BP][128];
  __shared__ __align__(16) float xin[BP][48];
  __shared__ __align__(16) float hs[BP][128];
  int tid = threadIdx.x;
  int qbase = blockIdx.x * BP;

  // trilinear features: thread = channel
  for (int p = 0; p < BP; ++p) {
    int q = qbase + p;
    int ray = q >> RAY_SHIFT;
    float t;
    if constexpr (OUTD == 2) t = ((float)(q & 3) + 0.5f) * 25.f;
    else                     t = dvals[q];
    float ux = unit[3*ray], uy = unit[3*ray+1], uz = unit[3*ray+2];
    float px, py, pz;
    point_world(ux,uy,uz,t,Tsi,px,py,pz);
    Tri tr = tri_setup(px,py,pz);
    zf[p][tid] = tri_gather(vf, mode, tid, tr);
  }
  // positional encoding input (42 dims): thread (p, d16) computes 3 dims
  {
    int p = tid >> 4, d16 = tid & 15;
    int q = qbase + p;
    int ray = q >> RAY_SHIFT;
    float t;
    if constexpr (OUTD == 2) t = ((float)(q & 3) + 0.5f) * 25.f;
    else                     t = dvals[q];
    float ux = unit[3*ray], uy = unit[3*ray+1], uz = unit[3*ray+2];
    float px, py, pz;
    point_world(ux,uy,uz,t,Tsi,px,py,pz);
    #pragma unroll
    for (int jj = 0; jj < 3; ++jj) {
      int dd = d16*3 + jj;
      if (dd < 42) {
        float val;
        if (dd < 3) val = (dd==0)?px:((dd==1)?py:pz);
        else if (dd < 39) {
          int s = dd - 3;
          bool is_sin = (s < 18);
          if (!is_sin) s -= 18;
          int axis = s / 6, fi = s % 6;
          float base = (axis==0)?px:((axis==1)?py:pz);
          float arg = base * (float)(1 << fi);
          val = is_sin ? sinf(arg) : cosf(arg);
        } else {
          val = viewdir[3*ray + (dd-39)];
        }
        xin[p][dd] = val;
      }
    }
  }
  __syncthreads();

  float h[BP];
  {
    float bi = b_in[tid];
    #pragma unroll
    for (int p = 0; p < BP; ++p) h[p] = bi;
    for (int k4 = 0; k4 < 10; ++k4) {
      float w0v = w_in[(k4*4+0)*128 + tid];
      float w1v = w_in[(k4*4+1)*128 + tid];
      float w2v = w_in[(k4*4+2)*128 + tid];
      float w3v = w_in[(k4*4+3)*128 + tid];
      #pragma unroll
      for (int p = 0; p < BP; ++p) {
        float4 x4 = *(const float4*)(&xin[p][k4*4]);
        h[p] = fmaf(x4.x, w0v, h[p]);
        h[p] = fmaf(x4.y, w1v, h[p]);
        h[p] = fmaf(x4.z, w2v, h[p]);
        h[p] = fmaf(x4.w, w3v, h[p]);
      }
    }
    for (int k = 40; k < 42; ++k) {
      float w = w_in[k*128 + tid];
      #pragma unroll
      for (int p = 0; p < BP; ++p) h[p] = fmaf(xin[p][k], w, h[p]);
    }
  }
  for (int i = 0; i < 3; ++i) {
    {
      float bzv = bz[i*128 + tid];
      #pragma unroll
      for (int p = 0; p < BP; ++p) h[p] += bzv;
      mac128(zf, wz + i*16384 + tid, h);
    }
    __syncthreads();
    #pragma unroll
    for (int p = 0; p < BP; ++p) hs[p][tid] = relu_(h[p]);
    __syncthreads();
    float net[BP];
    {
      float b0v = b0[i*128 + tid];
      #pragma unroll
      for (int p = 0; p < BP; ++p) net[p] = b0v;
      mac128(hs, w0 + i*16384 + tid, net);
    }
    __syncthreads();
    #pragma unroll
    for (int p = 0; p < BP; ++p) hs[p][tid] = relu_(net[p]);
    __syncthreads();
    {
      float b1v = b1[i*128 + tid];
      #pragma unroll
      for (int p = 0; p < BP; ++p) h[p] += b1v;
      mac128(hs, w1 + i*16384 + tid, h);
    }
  }
  __syncthreads();
  #pragma unroll
  for (int p = 0; p < BP; ++p) hs[p][tid] = relu_(h[p]);
  __syncthreads();

  if (tid < BP*OUTD) {
    int p = tid / OUTD, j = tid % OUTD;
    float acc = b_out[j];
    for (int k = 0; k < 128; ++k) acc = fmaf(hs[p][k], w_out[k*OUTD + j], acc);
    int q = qbase + p;
    if constexpr (OUTD == 2) {
      int ray = q >> 2, g = q & 3;
      if (j == 0) means[ray*4+g] = fminf(fmaxf(((float)g + 0.5f)*25.f + acc, 0.5f), 100.f);
      else        stds[ray*4+g]  = 2.5f*sigmoid_(acc) + 0.1f;
    } else {
      outbuf[q*4 + j] = acc;
    }
  }
}

// ---------------- per-ray depth set: build + rank-sort 64 values ----------------
__global__ void k_sortd(const float* __restrict__ means, const float* __restrict__ stds,
                        const float* __restrict__ noise, float* __restrict__ dsort, int R){
  __shared__ float buf[4][64];
  int lr = threadIdx.x >> 6, p = threadIdx.x & 63;
  int ray = blockIdx.x*4 + lr;
  float val;
  if (p < 32) val = 0.5f + (float)p * (99.5f/31.f);
  else {
    int idx = p - 32, g = idx >> 3, s = idx & 7;
    float mu = means[ray*4+g], sd = stds[ray*4+g];
    val = fminf(fmaxf(mu + sd*noise[(ray*4+g)*8 + s], 0.5f), 100.f);
  }
  buf[lr][p] = val;
  __syncthreads();
  int rank = 0;
  for (int k = 0; k < 64; ++k) {
    float o = buf[lr][k];
    rank += (o < val) || (o == val && k < p);
  }
  dsort[ray*64 + rank] = val;
}

// ---------------- render + all losses per ray ----------------
__device__ __forceinline__ void bilin3(const float* __restrict__ img, float u, float v, float* out){
  u = fminf(fmaxf(u, 0.f), (float)(WIMG-1));
  v = fminf(fmaxf(v, 0.f), (float)(HIMG-1));
  int u0 = min(max((int)floorf(u),0), WIMG-2);
  int v0 = min(max((int)floorf(v),0), HIMG-2);
  float fu = u - (float)u0, fv = v - (float)v0;
  float w00=(1.f-fv)*(1.f-fu), w01=(1.f-fv)*fu, w10=fv*(1.f-fu), w11=fv*fu;
  #pragma unroll
  for (int c = 0; c < 3; ++c) {
    const float* b = img + (size_t)c*(HIMG*WIMG) + (size_t)v0*WIMG + u0;
    out[c] = w00*b[0] + w01*b[1] + w10*b[WIMG] + w11*b[WIMG+1];
  }
}

__global__ void k_render(const float* __restrict__ outbuf, const float* __restrict__ dsort,
                         const float* __restrict__ means, const float* __restrict__ stds,
                         const float* __restrict__ unit,
                         const float* __restrict__ img_src, const float* __restrict__ img_tgt,
                         const int* __restrict__ pix, const float* __restrict__ camK,
                         const float* __restrict__ Tst, float* __restrict__ rayloss, int R){
  int r = blockIdx.x*blockDim.x + threadIdx.x;
  if (r >= R) return;
  const float* ob = outbuf + (size_t)r*256;
  const float* dd = dsort + (size_t)r*64;
  float m0=means[r*4],m1=means[r*4+1],m2=means[r*4+2],m3=means[r*4+3];
  float s0=stds[r*4], s1=stds[r*4+1], s2=stds[r*4+2], s3=stds[r*4+3];
  float trans = 1.f, depth = 0.f, col0=0.f,col1=0.f,col2=0.f, kl=0.f;
  float dcur = dd[0];
  for (int p = 0; p < 64; ++p) {
    float dnext = (p < 63) ? dd[p+1] : 0.f;
    float delta = (p < 63) ? (dnext - dcur) : 1e10f;
    float sig = softplus_(ob[p*4]);
    float alpha = 1.f - __expf(-sig*delta);
    float w = alpha * trans;
    trans *= (1.f - alpha + 1e-10f);
    depth += w * dcur;
    col0 += w * sigmoid_(ob[p*4+1]);
    col1 += w * sigmoid_(ob[p*4+2]);
    col2 += w * sigmoid_(ob[p*4+3]);
    float t0=(dcur-m0)/s0, t1=(dcur-m1)/s1, t2=(dcur-m2)/s2, t3=(dcur-m3)/s3;
    float pm = 0.25f*0.3989422804014327f*(__expf(-0.5f*t0*t0)/s0 + __expf(-0.5f*t1*t1)/s1
                                        + __expf(-0.5f*t2*t2)/s2 + __expf(-0.5f*t3*t3)/s3);
    kl += w * (-__logf(pm + 1e-6f));
    dcur = dnext;
  }
  float ld = fminf(fminf(fabsf(m0-depth),fabsf(m1-depth)), fminf(fabsf(m2-depth),fabsf(m3-depth)));
  float src[3], tgt[3];
  float u = (float)pix[2*r], v = (float)pix[2*r+1];
  bilin3(img_src, u, v, src);
  float ux=unit[3*r],uy=unit[3*r+1],uz=unit[3*r+2];
  float pcx=ux*depth, pcy=uy*depth, pcz=uz*depth;
  float ptx = Tst[0]*pcx + Tst[1]*pcy + Tst[2]*pcz + Tst[3];
  float pty = Tst[4]*pcx + Tst[5]*pcy + Tst[6]*pcz + Tst[7];
  float ptz = Tst[8]*pcx + Tst[9]*pcy + Tst[10]*pcz + Tst[11];
  float prx = camK[0]*ptx + camK[1]*pty + camK[2]*ptz;
  float pry = camK[3]*ptx + camK[4]*pty + camK[5]*ptz;
  float prz = camK[6]*ptx + camK[7]*pty + camK[8]*ptz;
  prz = fmaxf(prz, 0.001f);
  bilin3(img_tgt, prx/prz, pry/prz, tgt);
  float lrepr = fabsf(src[0]-tgt[0])+fabsf(src[1]-tgt[1])+fabsf(src[2]-tgt[2]);
  float lcol  = fabsf(src[0]-col0)+fabsf(src[1]-col1)+fabsf(src[2]-col2);
  float invR = 1.f/(float)R;
  rayloss[r] = (lrepr + lcol) * (invR/3.f) + kl*invR + 0.01f*ld*invR;
}

__global__ void k_reduce(const float* __restrict__ rayloss, float* __restrict__ out, int R){
  __shared__ float sm[256];
  float acc = 0.f;
  for (int i = threadIdx.x; i < R; i += 256) acc += rayloss[i];
  sm[threadIdx.x] = acc;
  __syncthreads();
  for (int s = 128; s > 0; s >>= 1) {
    if ((int)threadIdx.x < s) sm[threadIdx.x] += sm[threadIdx.x + s];
    __syncthreads();
  }
  if (threadIdx.x == 0) out[0] = sm[0];
}

extern "C" void kernel_launch(void* const* d_in, const int* in_sizes, int n_in,
                              void* d_out, int out_size, void* d_ws, size_t ws_size,
                              hipStream_t stream)
{
  const float* bev   = (const float*)d_in[0];
  const float* camK  = (const float*)d_in[1];
  const float* img_s = (const float*)d_in[2];
  const float* img_t = (const float*)d_in[3];
  const float* Tsi   = (const float*)d_in[4];
  const float* Tst   = (const float*)d_in[5];
  const float* noise = (const float*)d_in[6];
  const int*   pix   = (const int*)d_in[7];
  const float* m_w_in=(const float*)d_in[8];  const float* m_b_in=(const float*)d_in[9];
  const float* m_wz  =(const float*)d_in[10]; const float* m_bz  =(const float*)d_in[11];
  const float* m_w0  =(const float*)d_in[12]; const float* m_b0  =(const float*)d_in[13];
  const float* m_w1  =(const float*)d_in[14]; const float* m_b1  =(const float*)d_in[15];
  const float* m_wo  =(const float*)d_in[16]; const float* m_bo  =(const float*)d_in[17];
  const float* g_w_in=(const float*)d_in[18]; const float* g_b_in=(const float*)d_in[19];
  const float* g_wz  =(const float*)d_in[20]; const float* g_bz  =(const float*)d_in[21];
  const float* g_w0  =(const float*)d_in[22]; const float* g_b0  =(const float*)d_in[23];
  const float* g_w1  =(const float*)d_in[24]; const float* g_b1  =(const float*)d_in[25];
  const float* g_wo  =(const float*)d_in[26]; const float* g_bo  =(const float*)d_in[27];

  int R = in_sizes[7] / 2;   // sampled_pixels is (R,2)
  float* ws = (float*)d_ws;
  size_t off = 0;
  float* unitb = ws + off; off += (size_t)R*3;
  float* vdirb = ws + off; off += (size_t)R*3;
  float* means = ws + off; off += (size_t)R*4;
  float* stds  = ws + off; off += (size_t)R*4;
  float* dsort = ws + off; off += (size_t)R*64;
  float* outbf = ws + off; off += (size_t)R*256;
  float* rlos  = ws + off; off += (size_t)R;
  off = (off + 255) & ~(size_t)255;
  float* vft   = ws + off;
  size_t need = (off + (size_t)16*128*128*128) * 4ull;
  int mode = (ws_size >= need) ? 1 : 0;
  const float* vfp = mode ? (const float*)vft : bev;

  if (mode) {
    dim3 g(4,4,2048), b(32,8);
    k_transpose<<<g,b,0,stream>>>(bev, vft);
  }
  k_rayinit<<<(R+255)/256,256,0,stream>>>(camK,pix,Tsi,unitb,vdirb,R);
  k_mlp<2,2><<<R*4/BP,128,0,stream>>>(vfp,mode,unitb,vdirb,Tsi,nullptr,
      g_w_in,g_b_in,g_wz,g_bz,g_w0,g_b0,g_w1,g_b1,g_wo,g_bo,
      means,stds,nullptr);
  k_sortd<<<R/4,256,0,stream>>>(means,stds,noise,dsort,R);
  k_mlp<4,6><<<R*64/BP,128,0,stream>>>(vfp,mode,unitb,vdirb,Tsi,dsort,
      m_w_in,m_b_in,m_wz,m_bz,m_w0,m_b0,m_w1,m_b1,m_wo,m_bo,
      nullptr,nullptr,outbf);
  k_render<<<(R+255)/256,256,0,stream>>>(outbf,dsort,means,stds,unitb,img_s,img_t,pix,camK,Tst,rlos,R);
  k_reduce<<<1,256,0,stream>>>(rlos,(float*)d_out,R);
}

// Round 2
// 598.086 us; speedup vs baseline: 3.5222x; 3.5222x over previous
//
#include <hip/hip_runtime.h>

typedef __attribute__((ext_vector_type(8))) short short8;
typedef __attribute__((ext_vector_type(4))) float f32x4;
typedef unsigned short ushort_t;

#define WIMG 1216
#define HIMG 352

__device__ __forceinline__ float relu_(float x){ return fmaxf(x, 0.f); }
__device__ __forceinline__ float sigmoid_(float x){ return 1.f/(1.f+__expf(-x)); }
__device__ __forceinline__ float softplus_(float x){
  return fmaxf(x,0.f) + log1pf(__expf(-fabsf(x)));
}
__device__ __forceinline__ ushort_t f2b(float x){
  union { float f; unsigned u; } v; v.f = x;
  unsigned r = v.u + 0x7FFF + ((v.u >> 16) & 1);
  return (ushort_t)(r >> 16);
}
__device__ __forceinline__ float b2f(ushort_t b){
  union { unsigned u; float f; } v; v.u = ((unsigned)b) << 16;
  return v.f;
}
__device__ __forceinline__ float b2f_lo(unsigned u){
  union { unsigned u; float f; } v; v.u = u << 16; return v.f;
}
__device__ __forceinline__ float b2f_hi(unsigned u){
  union { unsigned u; float f; } v; v.u = u & 0xFFFF0000u; return v.f;
}

// ---------- pack one net's weights into B-fragment order (bf16) ----------
// layout: 38 kstep-blocks of 4096 bf16: [w_in ks0,ks1][i=0: wz*4, w0*4, w1*4][i=1..][i=2..]
// within block: elem id e: nt=e>>9, lane=(e>>3)&63, j=e&7 ; value = W[k][n],
// k = ksbase + (lane>>4)*8 + j, n = nt*16 + (lane&15)
__global__ void k_pack(const float* __restrict__ w_in, const float* __restrict__ wz,
                       const float* __restrict__ w0, const float* __restrict__ w1,
                       ushort_t* __restrict__ pk){
  int id = blockIdx.x*256 + threadIdx.x;
  if (id >= 38*4096) return;
  int blk = id >> 12;
  int e = id & 4095;
  int nt = e >> 9, lane = (e >> 3) & 63, j = e & 7;
  int kloc = (lane >> 4)*8 + j;
  int n = nt*16 + (lane & 15);
  float val;
  if (blk < 2) {
    int k = blk*32 + kloc;
    val = (k < 42) ? w_in[k*128 + n] : 0.f;
  } else {
    int g = blk - 2;
    int i = g / 12, r = g % 12, m = r >> 2, ks = r & 3;
    int k = ks*32 + kloc;
    const float* src = (m==0 ? wz : (m==1 ? w0 : w1)) + i*16384;
    val = src[k*128 + n];
  }
  pk[id] = f2b(val);
}

// ---------- transpose bev (z,c,x,y) fp32 -> vf (z,x,y,c) bf16 ----------
__global__ void k_transpose(const float* __restrict__ src, ushort_t* __restrict__ dst){
  __shared__ float tile[32][33];
  int zx = blockIdx.z;
  int y0 = blockIdx.x * 32;
  int c0 = blockIdx.y * 32;
  int z = zx >> 7, x = zx & 127;
  const float* s = src + (size_t)z*2097152 + (size_t)x*128;
  for (int i = threadIdx.y; i < 32; i += 8)
    tile[i][threadIdx.x] = s[(size_t)(c0+i)*16384 + (size_t)(y0 + threadIdx.x)];
  __syncthreads();
  ushort_t* d = dst + ((size_t)zx*128 + y0)*128 + c0;
  int idx = threadIdx.y*32 + threadIdx.x;
  for (int it = 0; it < 2; ++it) {
    int lin = it*256 + idx;           // 0..511 = 32 y * 16 cpairs
    int y = lin >> 4, cp = lin & 15;
    ushort2 o;
    o.x = f2b(tile[cp*2][y]);
    o.y = f2b(tile[cp*2+1][y]);
    *(ushort2*)(d + (size_t)y*128 + cp*2) = o;
  }
}

// ---------- per-ray unit dirs + viewdirs ----------
__global__ void k_rayinit(const float* __restrict__ camK, const int* __restrict__ pix,
                          const float* __restrict__ Tsi,
                          float* __restrict__ unit, float* __restrict__ viewdir, int R){
  int r = blockIdx.x*blockDim.x + threadIdx.x;
  if (r >= R) return;
  float a=camK[0],b=camK[1],c=camK[2],d=camK[3],e=camK[4],f=camK[5],g=camK[6],h=camK[7],i=camK[8];
  float c00 = e*i-f*h, c01 = c*h-b*i, c02 = b*f-c*e;
  float c10 = f*g-d*i, c11 = a*i-c*g, c12 = c*d-a*f;
  float c20 = d*h-e*g, c21 = b*g-a*h, c22 = a*e-b*d;
  float det = a*c00 + b*c10 + c*c20;
  float id = 1.f/det;
  float u = (float)pix[2*r], v = (float)pix[2*r+1];
  float dx = (c00*u + c01*v + c02)*id;
  float dy = (c10*u + c11*v + c12)*id;
  float dz = (c20*u + c21*v + c22)*id;
  float n = sqrtf(dx*dx+dy*dy+dz*dz);
  dx/=n; dy/=n; dz/=n;
  unit[3*r]=dx; unit[3*r+1]=dy; unit[3*r+2]=dz;
  viewdir[3*r]   = Tsi[0]*dx + Tsi[1]*dy + Tsi[2]*dz;
  viewdir[3*r+1] = Tsi[4]*dx + Tsi[5]*dy + Tsi[6]*dz;
  viewdir[3*r+2] = Tsi[8]*dx + Tsi[9]*dy + Tsi[10]*dz;
}

// ---------- GEMM helper: wave owns cols [wave*32, wave*32+32), all 64 rows ----------
template<int KS>
__device__ __forceinline__ void gemm_acc(const ushort_t* lds, int pitch,
                                         const ushort_t* __restrict__ pkB,
                                         f32x4 acc[4][2], int wave, int lane)
{
  int l15 = lane & 15, quad = lane >> 4;
  short8 b[2*KS];
  #pragma unroll
  for (int ks = 0; ks < KS; ++ks)
    #pragma unroll
    for (int ct = 0; ct < 2; ++ct)
      b[ks*2+ct] = *(const short8*)(pkB + (size_t)((ks*8 + wave*2 + ct)*64 + lane)*8);
  #pragma unroll
  for (int ks = 0; ks < KS; ++ks) {
    short8 a[4];
    #pragma unroll
    for (int rt = 0; rt < 4; ++rt)
      a[rt] = *(const short8*)(lds + (rt*16 + l15)*pitch + ks*32 + quad*8);
    #pragma unroll
    for (int rt = 0; rt < 4; ++rt)
      #pragma unroll
      for (int ct = 0; ct < 2; ++ct)
        acc[rt][ct] = __builtin_amdgcn_mfma_f32_16x16x32_bf16(a[rt], b[ks*2+ct], acc[rt][ct], 0,0,0);
  }
}

__device__ __forceinline__ void store_relu(ushort_t* buf, const f32x4 acc[4][2], int wave, int lane){
  int l15 = lane & 15, quad = lane >> 4;
  #pragma unroll
  for (int rt = 0; rt < 4; ++rt)
    #pragma unroll
    for (int ct = 0; ct < 2; ++ct) {
      int n = (wave*2+ct)*16 + l15;
      #pragma unroll
      for (int r = 0; r < 4; ++r) {
        int p = rt*16 + quad*4 + r;
        buf[p*136 + n] = f2b(fmaxf(acc[rt][ct][r], 0.f));
      }
    }
}

// ---------- fused trilinear + PE + resnet (MFMA bf16) ----------
// 64 points per block, 256 threads (4 waves)
template<int OUTD, int RAY_SHIFT>
__global__ __launch_bounds__(256)
void k_fused(const ushort_t* __restrict__ vfh, const float* __restrict__ vf0, int mode,
             const float* __restrict__ unit, const float* __restrict__ viewdir,
             const float* __restrict__ Tsi, const float* __restrict__ dvals,
             const ushort_t* __restrict__ pk,
             const float* __restrict__ b_in, const float* __restrict__ bzv,
             const float* __restrict__ b0v, const float* __restrict__ b1v,
             const float* __restrict__ w_out, const float* __restrict__ b_out,
             float* __restrict__ means, float* __restrict__ stds, float* __restrict__ outbuf)
{
  __shared__ int   sOff[64];
  __shared__ float sFx[64], sFy[64], sFz[64], sSc[64];
  __shared__ float sPx[64], sPy[64], sPz[64], sVx[64], sVy[64], sVz[64];
  __shared__ ushort_t xin[64*72];
  __shared__ ushort_t zf [64*136];
  __shared__ ushort_t bufA[64*136];
  __shared__ ushort_t bufB[64*136];

  int tid = threadIdx.x;
  int qbase = blockIdx.x * 64;

  if (tid < 64) {
    int q = qbase + tid;
    int ray = q >> RAY_SHIFT;
    float t;
    if constexpr (OUTD == 2) t = ((float)(q & 3) + 0.5f) * 25.f;
    else                     t = dvals[q];
    float ux = unit[3*ray], uy = unit[3*ray+1], uz = unit[3*ray+2];
    float wx=ux*t, wy=uy*t, wz=uz*t;
    float px = Tsi[0]*wx + Tsi[1]*wy + Tsi[2]*wz + Tsi[3];
    float py = Tsi[4]*wx + Tsi[5]*wy + Tsi[6]*wz + Tsi[7];
    float pz = Tsi[8]*wx + Tsi[9]*wy + Tsi[10]*wz + Tsi[11];
    sPx[tid]=px; sPy[tid]=py; sPz[tid]=pz;
    sVx[tid]=viewdir[3*ray]; sVy[tid]=viewdir[3*ray+1]; sVz[tid]=viewdir[3*ray+2];
    float gx = (px + 25.6f)*2.5f;
    float gy = (py + 25.6f)*2.5f;
    float gz = (pz + 2.0f)*2.5f;
    bool inb = (gx>=0.f)&&(gx<=127.f)&&(gy>=0.f)&&(gy<=127.f)&&(gz>=0.f)&&(gz<=15.f);
    gx = fminf(fmaxf(gx,0.f),127.f);
    gy = fminf(fmaxf(gy,0.f),127.f);
    gz = fminf(fmaxf(gz,0.f),15.f);
    int x0 = min(max((int)floorf(gx),0),126);
    int y0 = min(max((int)floorf(gy),0),126);
    int z0 = min(max((int)floorf(gz),0),14);
    sFx[tid]=gx-(float)x0; sFy[tid]=gy-(float)y0; sFz[tid]=gz-(float)z0;
    sSc[tid]= inb ? 1.f : 0.f;
    sOff[tid] = mode ? (((z0*128 + x0)*128 + y0)*128)
                     : (z0*2097152 + x0*128 + y0);
  }
  __syncthreads();

  // trilinear gather -> zf (bf16), 2 channels per thread-iter
  for (int it = 0; it < 16; ++it) {
    int lin = it*256 + tid;
    int p = lin >> 6, cp = lin & 63, c = cp*2;
    float fx=sFx[p], fy=sFy[p], fz=sFz[p], sc=sSc[p];
    float w000=(1.f-fz)*(1.f-fx)*(1.f-fy), w001=(1.f-fz)*(1.f-fx)*fy;
    float w010=(1.f-fz)*fx*(1.f-fy),       w011=(1.f-fz)*fx*fy;
    float w100=fz*(1.f-fx)*(1.f-fy),       w101=fz*(1.f-fx)*fy;
    float w110=fz*fx*(1.f-fy),             w111=fz*fx*fy;
    float r0, r1;
    if (mode) {
      const ushort_t* b = vfh + sOff[p] + c;
      unsigned v000 = *(const unsigned*)(b);
      unsigned v001 = *(const unsigned*)(b + 128);
      unsigned v010 = *(const unsigned*)(b + 16384);
      unsigned v011 = *(const unsigned*)(b + 16384 + 128);
      unsigned v100 = *(const unsigned*)(b + 2097152);
      unsigned v101 = *(const unsigned*)(b + 2097152 + 128);
      unsigned v110 = *(const unsigned*)(b + 2097152 + 16384);
      unsigned v111 = *(const unsigned*)(b + 2097152 + 16384 + 128);
      r0 = (w000*b2f_lo(v000) + w001*b2f_lo(v001) + w010*b2f_lo(v010) + w011*b2f_lo(v011)
          + w100*b2f_lo(v100) + w101*b2f_lo(v101) + w110*b2f_lo(v110) + w111*b2f_lo(v111)) * sc;
      r1 = (w000*b2f_hi(v000) + w001*b2f_hi(v001) + w010*b2f_hi(v010) + w011*b2f_hi(v011)
          + w100*b2f_hi(v100) + w101*b2f_hi(v101) + w110*b2f_hi(v110) + w111*b2f_hi(v111)) * sc;
    } else {
      const float* b = vf0 + sOff[p] + c*16384;
      r0 = (w000*b[0] + w001*b[1] + w010*b[128] + w011*b[129]
          + w100*b[2097152] + w101*b[2097153] + w110*b[2097280] + w111*b[2097281]) * sc;
      const float* b2 = b + 16384;
      r1 = (w000*b2[0] + w001*b2[1] + w010*b2[128] + w011*b2[129]
          + w100*b2[2097152] + w101*b2[2097153] + w110*b2[2097280] + w111*b2[2097281]) * sc;
    }
    ushort2 o; o.x = f2b(r0); o.y = f2b(r1);
    *(ushort2*)(zf + p*136 + c) = o;
  }

  // PE inputs -> xin (bf16), dims 42..63 zero
  for (int it = 0; it < 16; ++it) {
    int lin = it*256 + tid;
    int p = lin >> 6, d = lin & 63;
    float val = 0.f;
    if (d < 3)      val = (d==0)?sPx[p]:((d==1)?sPy[p]:sPz[p]);
    else if (d < 39) {
      int s = d - 3; bool isSin = (s < 18); if (!isSin) s -= 18;
      int axis = s/6, fi = s%6;
      float base = (axis==0)?sPx[p]:((axis==1)?sPy[p]:sPz[p]);
      float arg = base * (float)(1 << fi);
      val = isSin ? __sinf(arg) : __cosf(arg);
    } else if (d < 42) {
      val = (d==39)?sVx[p]:((d==40)?sVy[p]:sVz[p]);
    }
    xin[p*72 + d] = f2b(val);
  }
  __syncthreads();

  int wave = tid >> 6, lane = tid & 63;
  int l15 = lane & 15;
  int n0 = (wave*2)*16 + l15;          // col for ct=0 ; ct=1 is +16

  f32x4 h[4][2];
  {
    float bi0 = b_in[n0], bi1 = b_in[n0+16];
    #pragma unroll
    for (int rt = 0; rt < 4; ++rt) {
      h[rt][0] = (f32x4){bi0,bi0,bi0,bi0};
      h[rt][1] = (f32x4){bi1,bi1,bi1,bi1};
    }
  }
  gemm_acc<2>(xin, 72, pk, h, wave, lane);

  const ushort_t* pkl = pk + 2*4096;
  #pragma unroll 1
  for (int i = 0; i < 3; ++i) {
    gemm_acc<4>(zf, 136, pkl + (size_t)(i*12)*4096, h, wave, lane);
    {
      float z0b = bzv[i*128 + n0], z1b = bzv[i*128 + n0 + 16];
      #pragma unroll
      for (int rt = 0; rt < 4; ++rt) { h[rt][0] += z0b; h[rt][1] += z1b; }
    }
    __syncthreads();
    store_relu(bufA, h, wave, lane);
    __syncthreads();
    f32x4 net[4][2];
    {
      float c0b = b0v[i*128 + n0], c1b = b0v[i*128 + n0 + 16];
      #pragma unroll
      for (int rt = 0; rt < 4; ++rt) {
        net[rt][0] = (f32x4){c0b,c0b,c0b,c0b};
        net[rt][1] = (f32x4){c1b,c1b,c1b,c1b};
      }
    }
    gemm_acc<4>(bufA, 136, pkl + (size_t)(i*12+4)*4096, net, wave, lane);
    __syncthreads();
    store_relu(bufB, net, wave, lane);
    __syncthreads();
    gemm_acc<4>(bufB, 136, pkl + (size_t)(i*12+8)*4096, h, wave, lane);
    {
      float o0b = b1v[i*128 + n0], o1b = b1v[i*128 + n0 + 16];
      #pragma unroll
      for (int rt = 0; rt < 4; ++rt) { h[rt][0] += o0b; h[rt][1] += o1b; }
    }
  }
  __syncthreads();
  store_relu(bufA, h, wave, lane);
  __syncthreads();

  if constexpr (OUTD == 4) {
    int p = tid >> 2, j = tid & 3;
    float acc = b_out[j];
    #pragma unroll 4
    for (int k4 = 0; k4 < 32; ++k4) {
      ushort4 v = *(const ushort4*)(bufA + p*136 + k4*4);
      acc = fmaf(b2f(v.x), w_out[(k4*4+0)*4 + j], acc);
      acc = fmaf(b2f(v.y), w_out[(k4*4+1)*4 + j], acc);
      acc = fmaf(b2f(v.z), w_out[(k4*4+2)*4 + j], acc);
      acc = fmaf(b2f(v.w), w_out[(k4*4+3)*4 + j], acc);
    }
    outbuf[(size_t)(qbase + p)*4 + j] = acc;
  } else {
    if (tid < 128) {
      int p = tid >> 1, j = tid & 1;
      float acc = b_out[j];
      #pragma unroll 4
      for (int k4 = 0; k4 < 32; ++k4) {
        ushort4 v = *(const ushort4*)(bufA + p*136 + k4*4);
        acc = fmaf(b2f(v.x), w_out[(k4*4+0)*2 + j], acc);
        acc = fmaf(b2f(v.y), w_out[(k4*4+1)*2 + j], acc);
        acc = fmaf(b2f(v.z), w_out[(k4*4+2)*2 + j], acc);
        acc = fmaf(b2f(v.w), w_out[(k4*4+3)*2 + j], acc);
      }
      int q = qbase + p, ray = q >> 2, g = q & 3;
      if (j == 0) means[ray*4+g] = fminf(fmaxf(((float)g + 0.5f)*25.f + acc, 0.5f), 100.f);
      else        stds[ray*4+g]  = 2.5f*sigmoid_(acc) + 0.1f;
    }
  }
}

// ---------- per-ray depth set: build + rank-sort 64 values ----------
__global__ void k_sortd(const float* __restrict__ means, const float* __restrict__ stds,
                        const float* __restrict__ noise, float* __restrict__ dsort, int R){
  __shared__ float buf[4][64];
  int lr = threadIdx.x >> 6, p = threadIdx.x & 63;
  int ray = blockIdx.x*4 + lr;
  float val;
  if (p < 32) val = 0.5f + (float)p * (99.5f/31.f);
  else {
    int idx = p - 32, g = idx >> 3, s = idx & 7;
    float mu = means[ray*4+g], sd = stds[ray*4+g];
    val = fminf(fmaxf(mu + sd*noise[(ray*4+g)*8 + s], 0.5f), 100.f);
  }
  buf[lr][p] = val;
  __syncthreads();
  int rank = 0;
  for (int k = 0; k < 64; ++k) {
    float o = buf[lr][k];
    rank += (o < val) || (o == val && k < p);
  }
  dsort[ray*64 + rank] = val;
}

// ---------- render + losses ----------
__device__ __forceinline__ void bilin3(const float* __restrict__ img, float u, float v, float* out){
  u = fminf(fmaxf(u, 0.f), (float)(WIMG-1));
  v = fminf(fmaxf(v, 0.f), (float)(HIMG-1));
  int u0 = min(max((int)floorf(u),0), WIMG-2);
  int v0 = min(max((int)floorf(v),0), HIMG-2);
  float fu = u - (float)u0, fv = v - (float)v0;
  float w00=(1.f-fv)*(1.f-fu), w01=(1.f-fv)*fu, w10=fv*(1.f-fu), w11=fv*fu;
  #pragma unroll
  for (int c = 0; c < 3; ++c) {
    const float* b = img + (size_t)c*(HIMG*WIMG) + (size_t)v0*WIMG + u0;
    out[c] = w00*b[0] + w01*b[1] + w10*b[WIMG] + w11*b[WIMG+1];
  }
}

__global__ void k_render(const float* __restrict__ outbuf, const float* __restrict__ dsort,
                         const float* __restrict__ means, const float* __restrict__ stds,
                         const float* __restrict__ unit,
                         const float* __restrict__ img_src, const float* __restrict__ img_tgt,
                         const int* __restrict__ pix, const float* __restrict__ camK,
                         const float* __restrict__ Tst, float* __restrict__ rayloss, int R){
  int r = blockIdx.x*blockDim.x + threadIdx.x;
  if (r >= R) return;
  const float* ob = outbuf + (size_t)r*256;
  const float* dd = dsort + (size_t)r*64;
  float m0=means[r*4],m1=means[r*4+1],m2=means[r*4+2],m3=means[r*4+3];
  float s0=stds[r*4], s1=stds[r*4+1], s2=stds[r*4+2], s3=stds[r*4+3];
  float trans = 1.f, depth = 0.f, col0=0.f,col1=0.f,col2=0.f, kl=0.f;
  float dcur = dd[0];
  for (int p = 0; p < 64; ++p) {
    float dnext = (p < 63) ? dd[p+1] : 0.f;
    float delta = (p < 63) ? (dnext - dcur) : 1e10f;
    float sig = softplus_(ob[p*4]);
    float alpha = 1.f - __expf(-sig*delta);
    float w = alpha * trans;
    trans *= (1.f - alpha + 1e-10f);
    depth += w * dcur;
    col0 += w * sigmoid_(ob[p*4+1]);
    col1 += w * sigmoid_(ob[p*4+2]);
    col2 += w * sigmoid_(ob[p*4+3]);
    float t0=(dcur-m0)/s0, t1=(dcur-m1)/s1, t2=(dcur-m2)/s2, t3=(dcur-m3)/s3;
    float pm = 0.25f*0.3989422804014327f*(__expf(-0.5f*t0*t0)/s0 + __expf(-0.5f*t1*t1)/s1
                                        + __expf(-0.5f*t2*t2)/s2 + __expf(-0.5f*t3*t3)/s3);
    kl += w * (-__logf(pm + 1e-6f));
    dcur = dnext;
  }
  float ld = fminf(fminf(fabsf(m0-depth),fabsf(m1-depth)), fminf(fabsf(m2-depth),fabsf(m3-depth)));
  float src[3], tgt[3];
  float u = (float)pix[2*r], v = (float)pix[2*r+1];
  bilin3(img_src, u, v, src);
  float ux=unit[3*r],uy=unit[3*r+1],uz=unit[3*r+2];
  float pcx=ux*depth, pcy=uy*depth, pcz=uz*depth;
  float ptx = Tst[0]*pcx + Tst[1]*pcy + Tst[2]*pcz + Tst[3];
  float pty = Tst[4]*pcx + Tst[5]*pcy + Tst[6]*pcz + Tst[7];
  float ptz = Tst[8]*pcx + Tst[9]*pcy + Tst[10]*pcz + Tst[11];
  float prx = camK[0]*ptx + camK[1]*pty + camK[2]*ptz;
  float pry = camK[3]*ptx + camK[4]*pty + camK[5]*ptz;
  float prz = camK[6]*ptx + camK[7]*pty + camK[8]*ptz;
  prz = fmaxf(prz, 0.001f);
  bilin3(img_tgt, prx/prz, pry/prz, tgt);
  float lrepr = fabsf(src[0]-tgt[0])+fabsf(src[1]-tgt[1])+fabsf(src[2]-tgt[2]);
  float lcol  = fabsf(src[0]-col0)+fabsf(src[1]-col1)+fabsf(src[2]-col2);
  float invR = 1.f/(float)R;
  rayloss[r] = (lrepr + lcol) * (invR/3.f) + kl*invR + 0.01f*ld*invR;
}

__global__ void k_reduce(const float* __restrict__ rayloss, float* __restrict__ out, int R){
  __shared__ float sm[256];
  float acc = 0.f;
  for (int i = threadIdx.x; i < R; i += 256) acc += rayloss[i];
  sm[threadIdx.x] = acc;
  __syncthreads();
  for (int s = 128; s > 0; s >>= 1) {
    if ((int)threadIdx.x < s) sm[threadIdx.x] += sm[threadIdx.x + s];
    __syncthreads();
  }
  if (threadIdx.x == 0) out[0] = sm[0];
}

extern "C" void kernel_launch(void* const* d_in, const int* in_sizes, int n_in,
                              void* d_out, int out_size, void* d_ws, size_t ws_size,
                              hipStream_t stream)
{
  const float* bev   = (const float*)d_in[0];
  const float* camK  = (const float*)d_in[1];
  const float* img_s = (const float*)d_in[2];
  const float* img_t = (const float*)d_in[3];
  const float* Tsi   = (const float*)d_in[4];
  const float* Tst   = (const float*)d_in[5];
  const float* noise = (const float*)d_in[6];
  const int*   pix   = (const int*)d_in[7];
  const float* m_w_in=(const float*)d_in[8];  const float* m_b_in=(const float*)d_in[9];
  const float* m_wz  =(const float*)d_in[10]; const float* m_bz  =(const float*)d_in[11];
  const float* m_w0  =(const float*)d_in[12]; const float* m_b0  =(const float*)d_in[13];
  const float* m_w1  =(const float*)d_in[14]; const float* m_b1  =(const float*)d_in[15];
  const float* m_wo  =(const float*)d_in[16]; const float* m_bo  =(const float*)d_in[17];
  const float* g_w_in=(const float*)d_in[18]; const float* g_b_in=(const float*)d_in[19];
  const float* g_wz  =(const float*)d_in[20]; const float* g_bz  =(const float*)d_in[21];
  const float* g_w0  =(const float*)d_in[22]; const float* g_b0  =(const float*)d_in[23];
  const float* g_w1  =(const float*)d_in[24]; const float* g_b1  =(const float*)d_in[25];
  const float* g_wo  =(const float*)d_in[26]; const float* g_bo  =(const float*)d_in[27];

  int R = in_sizes[7] / 2;
  float* ws = (float*)d_ws;
  size_t off = 0;
  float* unitb = ws + off; off += (size_t)R*3;
  float* vdirb = ws + off; off += (size_t)R*3;
  float* means = ws + off; off += (size_t)R*4;
  float* stds  = ws + off; off += (size_t)R*4;
  float* dsort = ws + off; off += (size_t)R*64;
  float* outbf = ws + off; off += (size_t)R*256;
  float* rlos  = ws + off; off += (size_t)R;
  ushort_t* pkM = (ushort_t*)(ws + off);
  ushort_t* pkG = pkM + 38*4096;
  off += 38*4096 + 64;               // 2 nets * 38 blocks * 4096 bf16 = 38*4096 floats
  off = (off + 63) & ~(size_t)63;    // 256B align
  ushort_t* vfh = (ushort_t*)(ws + off);
  size_t need = off*4ull + (size_t)16*128*128*128*2ull;
  int mode = (ws_size >= need) ? 1 : 0;

  k_pack<<<608,256,0,stream>>>(m_w_in, m_wz, m_w0, m_w1, pkM);
  k_pack<<<608,256,0,stream>>>(g_w_in, g_wz, g_w0, g_w1, pkG);
  if (mode) {
    dim3 g(4,4,2048), b(32,8);
    k_transpose<<<g,b,0,stream>>>(bev, vfh);
  }
  k_rayinit<<<(R+255)/256,256,0,stream>>>(camK,pix,Tsi,unitb,vdirb,R);
  k_fused<2,2><<<R/16,256,0,stream>>>(vfh,bev,mode,unitb,vdirb,Tsi,nullptr,pkG,
      g_b_in,g_bz,g_b0,g_b1,g_wo,g_bo, means,stds,nullptr);
  k_sortd<<<R/4,256,0,stream>>>(means,stds,noise,dsort,R);
  k_fused<4,6><<<R,256,0,stream>>>(vfh,bev,mode,unitb,vdirb,Tsi,dsort,pkM,
      m_b_in,m_bz,m_b0,m_b1,m_wo,m_bo, nullptr,nullptr,outbf);
  k_render<<<(R+255)/256,256,0,stream>>>(outbf,dsort,means,stds,unitb,img_s,img_t,pix,camK,Tst,rlos,R);
  k_reduce<<<1,256,0,stream>>>(rlos,(float*)d_out,R);
}

// Round 3
// 483.117 us; speedup vs baseline: 4.3604x; 1.2380x over previous
//
#include <hip/hip_runtime.h>

typedef __attribute__((ext_vector_type(8))) short short8;
typedef __attribute__((ext_vector_type(4))) float f32x4;
typedef unsigned short ushort_t;

#define WIMG 1216
#define HIMG 352

__device__ __forceinline__ float sigmoid_(float x){ return 1.f/(1.f+__expf(-x)); }
__device__ __forceinline__ float softplus_(float x){
  return fmaxf(x,0.f) + log1pf(__expf(-fabsf(x)));
}
// exact RNE (used only for weight packing)
__device__ __forceinline__ ushort_t f2b(float x){
  union { float f; unsigned u; } v; v.f = x;
  unsigned r = v.u + 0x7FFF + ((v.u >> 16) & 1);
  return (ushort_t)(r >> 16);
}
// cheap round-half-up (activations; <=1ulp bias, fine at our tolerance)
__device__ __forceinline__ ushort_t f2b_fast(float x){
  union { float f; unsigned u; } v; v.f = x;
  return (ushort_t)((v.u + 0x8000u) >> 16);
}
__device__ __forceinline__ unsigned pack2bf(float a, float b){
  union { float f; unsigned u; } va, vb; va.f = a; vb.f = b;
  return ((va.u + 0x8000u) >> 16) | ((vb.u + 0x8000u) & 0xFFFF0000u);
}
__device__ __forceinline__ float b2f(ushort_t b){
  union { unsigned u; float f; } v; v.u = ((unsigned)b) << 16;
  return v.f;
}
__device__ __forceinline__ float b2f_lo(unsigned u){
  union { unsigned u; float f; } v; v.u = u << 16; return v.f;
}
__device__ __forceinline__ float b2f_hi(unsigned u){
  union { unsigned u; float f; } v; v.u = u & 0xFFFF0000u; return v.f;
}

// ---------- pack weights into B-fragment order (bf16) ----------
// blocks 0..37: 4096 bf16 each: [w_in ks0,ks1][i: wz*4, w0*4, w1*4]*3
//   e: nt=e>>9, lane=(e>>3)&63, j=e&7 ; k=ksbase+(lane>>4)*8+j, n=nt*16+(lane&15)
// block 38: w_out as one 16-col zero-padded n-tile: e<2048: ks=e>>9, k=ks*32+(lane>>4)*8+j, n=lane&15
__global__ void k_pack(const float* __restrict__ w_in, const float* __restrict__ wz,
                       const float* __restrict__ w0, const float* __restrict__ w1,
                       const float* __restrict__ w_out, int outd,
                       ushort_t* __restrict__ pk){
  int id = blockIdx.x*256 + threadIdx.x;
  if (id >= 39*4096) return;
  int blk = id >> 12;
  int e = id & 4095;
  float val = 0.f;
  if (blk < 38) {
    int nt = e >> 9, lane = (e >> 3) & 63, j = e & 7;
    int kloc = (lane >> 4)*8 + j;
    int n = nt*16 + (lane & 15);
    if (blk < 2) {
      int k = blk*32 + kloc;
      val = (k < 42) ? w_in[k*128 + n] : 0.f;
    } else {
      int g = blk - 2;
      int i = g / 12, r = g % 12, m = r >> 2, ks = r & 3;
      int k = ks*32 + kloc;
      const float* src = (m==0 ? wz : (m==1 ? w0 : w1)) + i*16384;
      val = src[k*128 + n];
    }
  } else if (e < 2048) {
    int ks = e >> 9, lane = (e >> 3) & 63, j = e & 7;
    int k = ks*32 + (lane >> 4)*8 + j;
    int n = lane & 15;
    val = (n < outd) ? w_out[k*outd + n] : 0.f;
  }
  pk[id] = f2b(val);
}

// ---------- transpose bev (z,c,x,y) fp32 -> vf (z,x,y,c) bf16 ----------
__global__ void k_transpose(const float* __restrict__ src, ushort_t* __restrict__ dst){
  __shared__ float tile[32][33];
  int zx = blockIdx.z;
  int y0 = blockIdx.x * 32;
  int c0 = blockIdx.y * 32;
  int z = zx >> 7, x = zx & 127;
  const float* s = src + (size_t)z*2097152 + (size_t)x*128;
  for (int i = threadIdx.y; i < 32; i += 8)
    tile[i][threadIdx.x] = s[(size_t)(c0+i)*16384 + (size_t)(y0 + threadIdx.x)];
  __syncthreads();
  ushort_t* d = dst + ((size_t)zx*128 + y0)*128 + c0;
  int idx = threadIdx.y*32 + threadIdx.x;
  for (int it = 0; it < 2; ++it) {
    int lin = it*256 + idx;           // 0..511 = 32 y * 16 cpairs
    int y = lin >> 4, cp = lin & 15;
    unsigned o = pack2bf(tile[cp*2][y], tile[cp*2+1][y]);
    *(unsigned*)(d + (size_t)y*128 + cp*2) = o;
  }
}

// ---------- per-ray unit dirs + viewdirs ----------
__global__ void k_rayinit(const float* __restrict__ camK, const int* __restrict__ pix,
                          const float* __restrict__ Tsi,
                          float* __restrict__ unit, float* __restrict__ viewdir, int R){
  int r = blockIdx.x*blockDim.x + threadIdx.x;
  if (r >= R) return;
  float a=camK[0],b=camK[1],c=camK[2],d=camK[3],e=camK[4],f=camK[5],g=camK[6],h=camK[7],i=camK[8];
  float c00 = e*i-f*h, c01 = c*h-b*i, c02 = b*f-c*e;
  float c10 = f*g-d*i, c11 = a*i-c*g, c12 = c*d-a*f;
  float c20 = d*h-e*g, c21 = b*g-a*h, c22 = a*e-b*d;
  float det = a*c00 + b*c10 + c*c20;
  float id = 1.f/det;
  float u = (float)pix[2*r], v = (float)pix[2*r+1];
  float dx = (c00*u + c01*v + c02)*id;
  float dy = (c10*u + c11*v + c12)*id;
  float dz = (c20*u + c21*v + c22)*id;
  float n = sqrtf(dx*dx+dy*dy+dz*dz);
  dx/=n; dy/=n; dz/=n;
  unit[3*r]=dx; unit[3*r+1]=dy; unit[3*r+2]=dz;
  viewdir[3*r]   = Tsi[0]*dx + Tsi[1]*dy + Tsi[2]*dz;
  viewdir[3*r+1] = Tsi[4]*dx + Tsi[5]*dy + Tsi[6]*dz;
  viewdir[3*r+2] = Tsi[8]*dx + Tsi[9]*dy + Tsi[10]*dz;
}

// ---------- GEMM helper: wave owns cols [wave*32, wave*32+32), all 64 rows ----------
template<int KS>
__device__ __forceinline__ void gemm_acc(const ushort_t* lds, int pitch,
                                         const ushort_t* __restrict__ pkB,
                                         f32x4 acc[4][2], int wave, int lane)
{
  int l15 = lane & 15, quad = lane >> 4;
  short8 b[2*KS];
  #pragma unroll
  for (int ks = 0; ks < KS; ++ks)
    #pragma unroll
    for (int ct = 0; ct < 2; ++ct)
      b[ks*2+ct] = *(const short8*)(pkB + (size_t)((ks*8 + wave*2 + ct)*64 + lane)*8);
  #pragma unroll
  for (int ks = 0; ks < KS; ++ks) {
    short8 a[4];
    #pragma unroll
    for (int rt = 0; rt < 4; ++rt)
      a[rt] = *(const short8*)(lds + (rt*16 + l15)*pitch + ks*32 + quad*8);
    #pragma unroll
    for (int rt = 0; rt < 4; ++rt)
      #pragma unroll
      for (int ct = 0; ct < 2; ++ct)
        acc[rt][ct] = __builtin_amdgcn_mfma_f32_16x16x32_bf16(a[rt], b[ks*2+ct], acc[rt][ct], 0,0,0);
  }
}

__device__ __forceinline__ void store_relu(ushort_t* buf, const f32x4 acc[4][2], int wave, int lane){
  int l15 = lane & 15, quad = lane >> 4;
  #pragma unroll
  for (int rt = 0; rt < 4; ++rt)
    #pragma unroll
    for (int ct = 0; ct < 2; ++ct) {
      int n = (wave*2+ct)*16 + l15;
      #pragma unroll
      for (int r = 0; r < 4; ++r) {
        int p = rt*16 + quad*4 + r;
        buf[p*136 + n] = f2b_fast(fmaxf(acc[rt][ct][r], 0.f));
      }
    }
}

// ---------- fused trilinear + PE + resnet (MFMA bf16) ----------
// 64 points per block, 256 threads (4 waves), single recycled work buffer
template<int OUTD, int RAY_SHIFT>
__global__ __launch_bounds__(256, 4)
void k_fused(const ushort_t* __restrict__ vfh, const float* __restrict__ vf0, int mode,
             const float* __restrict__ unit, const float* __restrict__ viewdir,
             const float* __restrict__ Tsi, const float* __restrict__ dvals,
             const ushort_t* __restrict__ pk,
             const float* __restrict__ b_in, const float* __restrict__ bzv,
             const float* __restrict__ b0v, const float* __restrict__ b1v,
             const float* __restrict__ b_out,
             float* __restrict__ means, float* __restrict__ stds, float* __restrict__ outbuf)
{
  __shared__ int   sOff[64];
  __shared__ float sFx[64], sFy[64], sFz[64], sSc[64];
  __shared__ float sPx[64], sPy[64], sPz[64], sVx[64], sVy[64], sVz[64];
  __shared__ ushort_t zf[64*136];
  __shared__ ushort_t Wb[64*136];    // holds xin (pitch 72), then recycled activation buffer

  int tid = threadIdx.x;
  int qbase = blockIdx.x * 64;

  if (tid < 64) {
    int q = qbase + tid;
    int ray = q >> RAY_SHIFT;
    float t;
    if constexpr (OUTD == 2) t = ((float)(q & 3) + 0.5f) * 25.f;
    else                     t = dvals[q];
    float ux = unit[3*ray], uy = unit[3*ray+1], uz = unit[3*ray+2];
    float wx=ux*t, wy=uy*t, wz=uz*t;
    float px = Tsi[0]*wx + Tsi[1]*wy + Tsi[2]*wz + Tsi[3];
    float py = Tsi[4]*wx + Tsi[5]*wy + Tsi[6]*wz + Tsi[7];
    float pz = Tsi[8]*wx + Tsi[9]*wy + Tsi[10]*wz + Tsi[11];
    sPx[tid]=px; sPy[tid]=py; sPz[tid]=pz;
    sVx[tid]=viewdir[3*ray]; sVy[tid]=viewdir[3*ray+1]; sVz[tid]=viewdir[3*ray+2];
    float gx = (px + 25.6f)*2.5f;
    float gy = (py + 25.6f)*2.5f;
    float gz = (pz + 2.0f)*2.5f;
    bool inb = (gx>=0.f)&&(gx<=127.f)&&(gy>=0.f)&&(gy<=127.f)&&(gz>=0.f)&&(gz<=15.f);
    gx = fminf(fmaxf(gx,0.f),127.f);
    gy = fminf(fmaxf(gy,0.f),127.f);
    gz = fminf(fmaxf(gz,0.f),15.f);
    int x0 = min(max((int)floorf(gx),0),126);
    int y0 = min(max((int)floorf(gy),0),126);
    int z0 = min(max((int)floorf(gz),0),14);
    sFx[tid]=gx-(float)x0; sFy[tid]=gy-(float)y0; sFz[tid]=gz-(float)z0;
    sSc[tid]= inb ? 1.f : 0.f;
    sOff[tid] = mode ? (((z0*128 + x0)*128 + y0)*128)
                     : (z0*2097152 + x0*128 + y0);
  }
  __syncthreads();

  // trilinear gather -> zf (bf16), 2 channels per thread-iter
  for (int it = 0; it < 16; ++it) {
    int lin = it*256 + tid;
    int p = lin >> 6, cp = lin & 63, c = cp*2;
    float fx=sFx[p], fy=sFy[p], fz=sFz[p], sc=sSc[p];
    float w000=(1.f-fz)*(1.f-fx)*(1.f-fy), w001=(1.f-fz)*(1.f-fx)*fy;
    float w010=(1.f-fz)*fx*(1.f-fy),       w011=(1.f-fz)*fx*fy;
    float w100=fz*(1.f-fx)*(1.f-fy),       w101=fz*(1.f-fx)*fy;
    float w110=fz*fx*(1.f-fy),             w111=fz*fx*fy;
    float r0, r1;
    if (mode) {
      const ushort_t* b = vfh + sOff[p] + c;
      unsigned v000 = *(const unsigned*)(b);
      unsigned v001 = *(const unsigned*)(b + 128);
      unsigned v010 = *(const unsigned*)(b + 16384);
      unsigned v011 = *(const unsigned*)(b + 16384 + 128);
      unsigned v100 = *(const unsigned*)(b + 2097152);
      unsigned v101 = *(const unsigned*)(b + 2097152 + 128);
      unsigned v110 = *(const unsigned*)(b + 2097152 + 16384);
      unsigned v111 = *(const unsigned*)(b + 2097152 + 16384 + 128);
      r0 = (w000*b2f_lo(v000) + w001*b2f_lo(v001) + w010*b2f_lo(v010) + w011*b2f_lo(v011)
          + w100*b2f_lo(v100) + w101*b2f_lo(v101) + w110*b2f_lo(v110) + w111*b2f_lo(v111)) * sc;
      r1 = (w000*b2f_hi(v000) + w001*b2f_hi(v001) + w010*b2f_hi(v010) + w011*b2f_hi(v011)
          + w100*b2f_hi(v100) + w101*b2f_hi(v101) + w110*b2f_hi(v110) + w111*b2f_hi(v111)) * sc;
    } else {
      const float* b = vf0 + sOff[p] + c*16384;
      r0 = (w000*b[0] + w001*b[1] + w010*b[128] + w011*b[129]
          + w100*b[2097152] + w101*b[2097153] + w110*b[2097280] + w111*b[2097281]) * sc;
      const float* b2 = b + 16384;
      r1 = (w000*b2[0] + w001*b2[1] + w010*b2[128] + w011*b2[129]
          + w100*b2[2097152] + w101*b2[2097153] + w110*b2[2097280] + w111*b2[2097281]) * sc;
    }
    *(unsigned*)(zf + p*136 + c) = pack2bf(r0, r1);
  }

  // PE inputs -> Wb as xin (pitch 72), dims 42..63 zero
  for (int it = 0; it < 16; ++it) {
    int lin = it*256 + tid;
    int p = lin >> 6, d = lin & 63;
    float val = 0.f;
    if (d < 3)      val = (d==0)?sPx[p]:((d==1)?sPy[p]:sPz[p]);
    else if (d < 39) {
      int s = d - 3; bool isSin = (s < 18); if (!isSin) s -= 18;
      int axis = s/6, fi = s%6;
      float base = (axis==0)?sPx[p]:((axis==1)?sPy[p]:sPz[p]);
      float arg = base * (float)(1 << fi);
      val = isSin ? __sinf(arg) : __cosf(arg);
    } else if (d < 42) {
      val = (d==39)?sVx[p]:((d==40)?sVy[p]:sVz[p]);
    }
    Wb[p*72 + d] = f2b_fast(val);
  }
  __syncthreads();

  int wave = tid >> 6, lane = tid & 63;
  int l15 = lane & 15, quad = lane >> 4;
  int n0 = (wave*2)*16 + l15;          // col for ct=0 ; ct=1 is +16

  f32x4 h[4][2];
  {
    float bi0 = b_in[n0], bi1 = b_in[n0+16];
    #pragma unroll
    for (int rt = 0; rt < 4; ++rt) {
      h[rt][0] = (f32x4){bi0,bi0,bi0,bi0};
      h[rt][1] = (f32x4){bi1,bi1,bi1,bi1};
    }
  }
  gemm_acc<2>(Wb, 72, pk, h, wave, lane);

  const ushort_t* pkl = pk + 2*4096;
  #pragma unroll 1
  for (int i = 0; i < 3; ++i) {
    gemm_acc<4>(zf, 136, pkl + (size_t)(i*12)*4096, h, wave, lane);
    {
      float z0b = bzv[i*128 + n0], z1b = bzv[i*128 + n0 + 16];
      #pragma unroll
      for (int rt = 0; rt < 4; ++rt) { h[rt][0] += z0b; h[rt][1] += z1b; }
    }
    __syncthreads();                 // all waves done reading Wb
    store_relu(Wb, h, wave, lane);
    __syncthreads();
    f32x4 net[4][2];
    {
      float c0b = b0v[i*128 + n0], c1b = b0v[i*128 + n0 + 16];
      #pragma unroll
      for (int rt = 0; rt < 4; ++rt) {
        net[rt][0] = (f32x4){c0b,c0b,c0b,c0b};
        net[rt][1] = (f32x4){c1b,c1b,c1b,c1b};
      }
    }
    gemm_acc<4>(Wb, 136, pkl + (size_t)(i*12+4)*4096, net, wave, lane);
    __syncthreads();
    store_relu(Wb, net, wave, lane);
    __syncthreads();
    gemm_acc<4>(Wb, 136, pkl + (size_t)(i*12+8)*4096, h, wave, lane);
    {
      float o0b = b1v[i*128 + n0], o1b = b1v[i*128 + n0 + 16];
      #pragma unroll
      for (int rt = 0; rt < 4; ++rt) { h[rt][0] += o0b; h[rt][1] += o1b; }
    }
  }
  __syncthreads();
  store_relu(Wb, h, wave, lane);
  __syncthreads();

  // epilogue: out = relu(h) @ w_out + b_out via one 16x16 MFMA tile per wave
  {
    const ushort_t* pkw = pk + 38*4096;
    float bj = (l15 < OUTD) ? b_out[l15] : 0.f;
    f32x4 oa = (f32x4){bj,bj,bj,bj};
    #pragma unroll
    for (int ks = 0; ks < 4; ++ks) {
      short8 a = *(const short8*)(Wb + (wave*16 + l15)*136 + ks*32 + quad*8);
      short8 b = *(const short8*)(pkw + (size_t)(ks*64 + lane)*8);
      oa = __builtin_amdgcn_mfma_f32_16x16x32_bf16(a, b, oa, 0,0,0);
    }
    if (l15 < OUTD) {
      #pragma unroll
      for (int r = 0; r < 4; ++r) {
        int p = wave*16 + quad*4 + r;
        int q = qbase + p;
        if constexpr (OUTD == 4) {
          outbuf[(size_t)q*4 + l15] = oa[r];
        } else {
          int ray = q >> 2, g = q & 3;
          if (l15 == 0) means[ray*4+g] = fminf(fmaxf(((float)g + 0.5f)*25.f + oa[r], 0.5f), 100.f);
          else          stds[ray*4+g]  = 2.5f*sigmoid_(oa[r]) + 0.1f;
        }
      }
    }
  }
}

// ---------- per-ray depth set: build + rank-sort 64 values ----------
__global__ void k_sortd(const float* __restrict__ means, const float* __restrict__ stds,
                        const float* __restrict__ noise, float* __restrict__ dsort, int R){
  __shared__ float buf[4][64];
  int lr = threadIdx.x >> 6, p = threadIdx.x & 63;
  int ray = blockIdx.x*4 + lr;
  float val;
  if (p < 32) val = 0.5f + (float)p * (99.5f/31.f);
  else {
    int idx = p - 32, g = idx >> 3, s = idx & 7;
    float mu = means[ray*4+g], sd = stds[ray*4+g];
    val = fminf(fmaxf(mu + sd*noise[(ray*4+g)*8 + s], 0.5f), 100.f);
  }
  buf[lr][p] = val;
  __syncthreads();
  int rank = 0;
  for (int k = 0; k < 64; ++k) {
    float o = buf[lr][k];
    rank += (o < val) || (o == val && k < p);
  }
  dsort[ray*64 + rank] = val;
}

// ---------- render + losses: one wave per ray, lane = sample ----------
__device__ __forceinline__ void bilin3(const float* __restrict__ img, float u, float v, float* out){
  u = fminf(fmaxf(u, 0.f), (float)(WIMG-1));
  v = fminf(fmaxf(v, 0.f), (float)(HIMG-1));
  int u0 = min(max((int)floorf(u),0), WIMG-2);
  int v0 = min(max((int)floorf(v),0), HIMG-2);
  float fu = u - (float)u0, fv = v - (float)v0;
  float w00=(1.f-fv)*(1.f-fu), w01=(1.f-fv)*fu, w10=fv*(1.f-fu), w11=fv*fu;
  #pragma unroll
  for (int c = 0; c < 3; ++c) {
    const float* b = img + (size_t)c*(HIMG*WIMG) + (size_t)v0*WIMG + u0;
    out[c] = w00*b[0] + w01*b[1] + w10*b[WIMG] + w11*b[WIMG+1];
  }
}

__global__ void k_render(const float* __restrict__ outbuf, const float* __restrict__ dsort,
                         const float* __restrict__ means, const float* __restrict__ stds,
                         const float* __restrict__ unit,
                         const float* __restrict__ img_src, const float* __restrict__ img_tgt,
                         const int* __restrict__ pix, const float* __restrict__ camK,
                         const float* __restrict__ Tst, float* __restrict__ rayloss, int R){
  int gid = blockIdx.x*blockDim.x + threadIdx.x;
  int r = gid >> 6, lane = gid & 63;
  if (r >= R) return;
  float d = dsort[(size_t)r*64 + lane];
  float dn = __shfl_down(d, 1);
  float delta = (lane < 63) ? (dn - d) : 1e10f;
  float4 o = *(const float4*)(outbuf + (size_t)r*256 + lane*4);
  float sig = softplus_(o.x);
  float alpha = 1.f - __expf(-sig*delta);
  float om = 1.f - alpha + 1e-10f;
  // inclusive prefix product, then shift to exclusive
  float prod = om;
  #pragma unroll
  for (int off = 1; off < 64; off <<= 1) {
    float v = __shfl_up(prod, off);
    if (lane >= off) prod *= v;
  }
  float texc = __shfl_up(prod, 1);
  if (lane == 0) texc = 1.f;
  float w = alpha * texc;
  float m0=means[r*4],m1=means[r*4+1],m2=means[r*4+2],m3=means[r*4+3];
  float s0=stds[r*4], s1=stds[r*4+1], s2=stds[r*4+2], s3=stds[r*4+3];
  float t0=(d-m0)/s0, t1=(d-m1)/s1, t2=(d-m2)/s2, t3=(d-m3)/s3;
  float pm = 0.25f*0.3989422804014327f*(__expf(-0.5f*t0*t0)/s0 + __expf(-0.5f*t1*t1)/s1
                                      + __expf(-0.5f*t2*t2)/s2 + __expf(-0.5f*t3*t3)/s3);
  float kl  = w * (-__logf(pm + 1e-6f));
  float dep = w * d;
  float c0 = w * sigmoid_(o.y);
  float c1 = w * sigmoid_(o.z);
  float c2 = w * sigmoid_(o.w);
  #pragma unroll
  for (int off = 32; off; off >>= 1) {
    dep += __shfl_xor(dep, off);
    c0  += __shfl_xor(c0, off);
    c1  += __shfl_xor(c1, off);
    c2  += __shfl_xor(c2, off);
    kl  += __shfl_xor(kl, off);
  }
  if (lane == 0) {
    float ld = fminf(fminf(fabsf(m0-dep),fabsf(m1-dep)), fminf(fabsf(m2-dep),fabsf(m3-dep)));
    float src[3], tgt[3];
    float u = (float)pix[2*r], v = (float)pix[2*r+1];
    bilin3(img_src, u, v, src);
    float ux=unit[3*r],uy=unit[3*r+1],uz=unit[3*r+2];
    float pcx=ux*dep, pcy=uy*dep, pcz=uz*dep;
    float ptx = Tst[0]*pcx + Tst[1]*pcy + Tst[2]*pcz + Tst[3];
    float pty = Tst[4]*pcx + Tst[5]*pcy + Tst[6]*pcz + Tst[7];
    float ptz = Tst[8]*pcx + Tst[9]*pcy + Tst[10]*pcz + Tst[11];
    float prx = camK[0]*ptx + camK[1]*pty + camK[2]*ptz;
    float pry = camK[3]*ptx + camK[4]*pty + camK[5]*ptz;
    float prz = camK[6]*ptx + camK[7]*pty + camK[8]*ptz;
    prz = fmaxf(prz, 0.001f);
    bilin3(img_tgt, prx/prz, pry/prz, tgt);
    float lrepr = fabsf(src[0]-tgt[0])+fabsf(src[1]-tgt[1])+fabsf(src[2]-tgt[2]);
    float lcol  = fabsf(src[0]-c0)+fabsf(src[1]-c1)+fabsf(src[2]-c2);
    float invR = 1.f/(float)R;
    rayloss[r] = (lrepr + lcol) * (invR/3.f) + kl*invR + 0.01f*ld*invR;
  }
}

__global__ void k_reduce(const float* __restrict__ rayloss, float* __restrict__ out, int R){
  __shared__ float sm[256];
  float acc = 0.f;
  for (int i = threadIdx.x; i < R; i += 256) acc += rayloss[i];
  sm[threadIdx.x] = acc;
  __syncthreads();
  for (int s = 128; s > 0; s >>= 1) {
    if ((int)threadIdx.x < s) sm[threadIdx.x] += sm[threadIdx.x + s];
    __syncthreads();
  }
  if (threadIdx.x == 0) out[0] = sm[0];
}

extern "C" void kernel_launch(void* const* d_in, const int* in_sizes, int n_in,
                              void* d_out, int out_size, void* d_ws, size_t ws_size,
                              hipStream_t stream)
{
  const float* bev   = (const float*)d_in[0];
  const float* camK  = (const float*)d_in[1];
  const float* img_s = (const float*)d_in[2];
  const float* img_t = (const float*)d_in[3];
  const float* Tsi   = (const float*)d_in[4];
  const float* Tst   = (const float*)d_in[5];
  const float* noise = (const float*)d_in[6];
  const int*   pix   = (const int*)d_in[7];
  const float* m_w_in=(const float*)d_in[8];  const float* m_b_in=(const float*)d_in[9];
  const float* m_wz  =(const float*)d_in[10]; const float* m_bz  =(const float*)d_in[11];
  const float* m_w0  =(const float*)d_in[12]; const float* m_b0  =(const float*)d_in[13];
  const float* m_w1  =(const float*)d_in[14]; const float* m_b1  =(const float*)d_in[15];
  const float* m_wo  =(const float*)d_in[16]; const float* m_bo  =(const float*)d_in[17];
  const float* g_w_in=(const float*)d_in[18]; const float* g_b_in=(const float*)d_in[19];
  const float* g_wz  =(const float*)d_in[20]; const float* g_bz  =(const float*)d_in[21];
  const float* g_w0  =(const float*)d_in[22]; const float* g_b0  =(const float*)d_in[23];
  const float* g_w1  =(const float*)d_in[24]; const float* g_b1  =(const float*)d_in[25];
  const float* g_wo  =(const float*)d_in[26]; const float* g_bo  =(const float*)d_in[27];

  int R = in_sizes[7] / 2;
  float* ws = (float*)d_ws;
  size_t off = 0;
  float* unitb = ws + off; off += (size_t)R*3;
  float* vdirb = ws + off; off += (size_t)R*3;
  float* means = ws + off; off += (size_t)R*4;
  float* stds  = ws + off; off += (size_t)R*4;
  float* dsort = ws + off; off += (size_t)R*64;
  float* outbf = ws + off; off += (size_t)R*256;
  float* rlos  = ws + off; off += (size_t)R;
  ushort_t* pkM = (ushort_t*)(ws + off);
  ushort_t* pkG = pkM + 39*4096;
  off += 39*4096 + 64;               // 2 nets * 39 blocks * 4096 bf16 = 39*4096 floats
  off = (off + 63) & ~(size_t)63;
  ushort_t* vfh = (ushort_t*)(ws + off);
  size_t need = off*4ull + (size_t)16*128*128*128*2ull;
  int mode = (ws_size >= need) ? 1 : 0;

  k_pack<<<624,256,0,stream>>>(m_w_in, m_wz, m_w0, m_w1, m_wo, 4, pkM);
  k_pack<<<624,256,0,stream>>>(g_w_in, g_wz, g_w0, g_w1, g_wo, 2, pkG);
  if (mode) {
    dim3 g(4,4,2048), b(32,8);
    k_transpose<<<g,b,0,stream>>>(bev, vfh);
  }
  k_rayinit<<<(R+255)/256,256,0,stream>>>(camK,pix,Tsi,unitb,vdirb,R);
  k_fused<2,2><<<R/16,256,0,stream>>>(vfh,bev,mode,unitb,vdirb,Tsi,nullptr,pkG,
      g_b_in,g_bz,g_b0,g_b1,g_bo, means,stds,nullptr);
  k_sortd<<<R/4,256,0,stream>>>(means,stds,noise,dsort,R);
  k_fused<4,6><<<R,256,0,stream>>>(vfh,bev,mode,unitb,vdirb,Tsi,dsort,pkM,
      m_b_in,m_bz,m_b0,m_b1,m_bo, nullptr,nullptr,outbf);
  k_render<<<R/4,256,0,stream>>>(outbf,dsort,means,stds,unitb,img_s,img_t,pix,camK,Tst,rlos,R);
  k_reduce<<<1,256,0,stream>>>(rlos,(float*)d_out,R);
}

// Round 4
// 458.768 us; speedup vs baseline: 4.5919x; 1.0531x over previous
//
#include <hip/hip_runtime.h>

typedef __attribute__((ext_vector_type(8))) short short8;
typedef __attribute__((ext_vector_type(4))) float f32x4;
typedef unsigned short ushort_t;

#define WIMG 1216
#define HIMG 352

__device__ __forceinline__ float sigmoid_(float x){ return 1.f/(1.f+__expf(-x)); }
__device__ __forceinline__ float softplus_(float x){
  return fmaxf(x,0.f) + log1pf(__expf(-fabsf(x)));
}
// exact RNE (weight packing only)
__device__ __forceinline__ ushort_t f2b(float x){
  union { float f; unsigned u; } v; v.f = x;
  unsigned r = v.u + 0x7FFF + ((v.u >> 16) & 1);
  return (ushort_t)(r >> 16);
}
__device__ __forceinline__ ushort_t f2b_fast(float x){
  union { float f; unsigned u; } v; v.f = x;
  return (ushort_t)((v.u + 0x8000u) >> 16);
}
// truncating pack of two f32 -> bf16x2 (3 int ops; compiler may fuse to v_perm)
__device__ __forceinline__ unsigned pack_trunc(float a, float b){
  union { float f; unsigned u; } va, vb; va.f = a; vb.f = b;
  return (va.u >> 16) | (vb.u & 0xFFFF0000u);
}
__device__ __forceinline__ float b2f_lo(unsigned u){
  union { unsigned u; float f; } v; v.u = u << 16; return v.f;
}
__device__ __forceinline__ float b2f_hi(unsigned u){
  union { unsigned u; float f; } v; v.u = u & 0xFFFF0000u; return v.f;
}

// ---------- pack weights (bf16). Same buffer serves as B-frags (old) or A-frags of W^T (new) ----------
// blocks 0..37: [w_in ks0,ks1][i: wz*4, w0*4, w1*4]*3 ; block 38: w_out (16-col zero-padded)
__global__ void k_pack(const float* __restrict__ w_in, const float* __restrict__ wz,
                       const float* __restrict__ w0, const float* __restrict__ w1,
                       const float* __restrict__ w_out, int outd,
                       ushort_t* __restrict__ pk){
  int id = blockIdx.x*256 + threadIdx.x;
  if (id >= 39*4096) return;
  int blk = id >> 12;
  int e = id & 4095;
  float val = 0.f;
  if (blk < 38) {
    int nt = e >> 9, lane = (e >> 3) & 63, j = e & 7;
    int kloc = (lane >> 4)*8 + j;
    int n = nt*16 + (lane & 15);
    if (blk < 2) {
      int k = blk*32 + kloc;
      val = (k < 42) ? w_in[k*128 + n] : 0.f;
    } else {
      int g = blk - 2;
      int i = g / 12, r = g % 12, m = r >> 2, ks = r & 3;
      int k = ks*32 + kloc;
      const float* src = (m==0 ? wz : (m==1 ? w0 : w1)) + i*16384;
      val = src[k*128 + n];
    }
  } else if (e < 2048) {
    int ks = e >> 9, lane = (e >> 3) & 63, j = e & 7;
    int k = ks*32 + (lane >> 4)*8 + j;
    int n = lane & 15;
    val = (n < outd) ? w_out[k*outd + n] : 0.f;
  }
  pk[id] = f2b(val);
}

// ---------- transpose bev (z,c,x,y) fp32 -> vf (z,x,y,c) bf16, non-temporal ----------
__global__ void k_transpose(const float* __restrict__ src, ushort_t* __restrict__ dst){
  __shared__ float tile[32][33];
  int zx = blockIdx.z;
  int y0 = blockIdx.x * 32;
  int c0 = blockIdx.y * 32;
  int z = zx >> 7, x = zx & 127;
  const float* s = src + (size_t)z*2097152 + (size_t)x*128;
  for (int i = threadIdx.y; i < 32; i += 8)
    tile[i][threadIdx.x] = __builtin_nontemporal_load(s + (size_t)(c0+i)*16384 + (size_t)(y0 + threadIdx.x));
  __syncthreads();
  ushort_t* d = dst + ((size_t)zx*128 + y0)*128 + c0;
  int idx = threadIdx.y*32 + threadIdx.x;
  for (int it = 0; it < 2; ++it) {
    int lin = it*256 + idx;           // 0..511 = 32 y * 16 cpairs
    int y = lin >> 4, cp = lin & 15;
    unsigned o = pack_trunc(tile[cp*2][y], tile[cp*2+1][y]);
    __builtin_nontemporal_store(o, (unsigned*)(d + (size_t)y*128 + cp*2));
  }
}

// ---------- per-ray unit dirs + viewdirs ----------
__global__ void k_rayinit(const float* __restrict__ camK, const int* __restrict__ pix,
                          const float* __restrict__ Tsi,
                          float* __restrict__ unit, float* __restrict__ viewdir, int R){
  int r = blockIdx.x*blockDim.x + threadIdx.x;
  if (r >= R) return;
  float a=camK[0],b=camK[1],c=camK[2],d=camK[3],e=camK[4],f=camK[5],g=camK[6],h=camK[7],i=camK[8];
  float c00 = e*i-f*h, c01 = c*h-b*i, c02 = b*f-c*e;
  float c10 = f*g-d*i, c11 = a*i-c*g, c12 = c*d-a*f;
  float c20 = d*h-e*g, c21 = b*g-a*h, c22 = a*e-b*d;
  float det = a*c00 + b*c10 + c*c20;
  float id = 1.f/det;
  float u = (float)pix[2*r], v = (float)pix[2*r+1];
  float dx = (c00*u + c01*v + c02)*id;
  float dy = (c10*u + c11*v + c12)*id;
  float dz = (c20*u + c21*v + c22)*id;
  float n = sqrtf(dx*dx+dy*dy+dz*dz);
  dx/=n; dy/=n; dz/=n;
  unit[3*r]=dx; unit[3*r+1]=dy; unit[3*r+2]=dz;
  viewdir[3*r]   = Tsi[0]*dx + Tsi[1]*dy + Tsi[2]*dz;
  viewdir[3*r+1] = Tsi[4]*dx + Tsi[5]*dy + Tsi[6]*dz;
  viewdir[3*r+2] = Tsi[8]*dx + Tsi[9]*dy + Tsi[10]*dz;
}

// ---------- transposed GEMM: D = W^T(A) x act^T(B). acc[ct][nt]; wave owns 32 out-channels ----------
template<int KS>
__device__ __forceinline__ void gemm_accT(const ushort_t* lds, int pitch,
                                          const ushort_t* __restrict__ pkW,
                                          f32x4 acc[2][4], int wave, int lane)
{
  int l15 = lane & 15, quad = lane >> 4;
  short8 w[KS][2];
  #pragma unroll
  for (int ks = 0; ks < KS; ++ks)
    #pragma unroll
    for (int ct = 0; ct < 2; ++ct)
      w[ks][ct] = *(const short8*)(pkW + (size_t)((ks*8 + wave*2 + ct)*64 + lane)*8);
  #pragma unroll
  for (int ks = 0; ks < KS; ++ks) {
    short8 b[4];
    #pragma unroll
    for (int nt = 0; nt < 4; ++nt)
      b[nt] = *(const short8*)(lds + (nt*16 + l15)*pitch + ks*32 + quad*8);
    #pragma unroll
    for (int ct = 0; ct < 2; ++ct)
      #pragma unroll
      for (int nt = 0; nt < 4; ++nt)
        acc[ct][nt] = __builtin_amdgcn_mfma_f32_16x16x32_bf16(w[ks][ct], b[nt], acc[ct][nt], 0,0,0);
  }
}

// lane's 4 acc values = 4 consecutive channels of one point -> one ds_write_b64 each
__device__ __forceinline__ void store_reluT(ushort_t* buf, const f32x4 acc[2][4], int wave, int lane){
  int l15 = lane & 15, quad = lane >> 4;
  #pragma unroll
  for (int ct = 0; ct < 2; ++ct)
    #pragma unroll
    for (int nt = 0; nt < 4; ++nt) {
      float r0 = fmaxf(acc[ct][nt][0], 0.f);
      float r1 = fmaxf(acc[ct][nt][1], 0.f);
      float r2 = fmaxf(acc[ct][nt][2], 0.f);
      float r3 = fmaxf(acc[ct][nt][3], 0.f);
      uint2 o; o.x = pack_trunc(r0, r1); o.y = pack_trunc(r2, r3);
      *(uint2*)(buf + (nt*16 + l15)*136 + (wave*2+ct)*16 + quad*4) = o;
    }
}

// ---------- fused trilinear + PE + resnet (MFMA bf16, transposed operands) ----------
template<int OUTD, int RAY_SHIFT>
__global__ __launch_bounds__(256, 4)
void k_fused(const ushort_t* __restrict__ vfh, const float* __restrict__ vf0, int mode,
             const float* __restrict__ unit, const float* __restrict__ viewdir,
             const float* __restrict__ Tsi, const float* __restrict__ dvals,
             const ushort_t* __restrict__ pk,
             const float* __restrict__ b_in, const float* __restrict__ bzv,
             const float* __restrict__ b0v, const float* __restrict__ b1v,
             const float* __restrict__ b_out,
             float* __restrict__ means, float* __restrict__ stds, float* __restrict__ outbuf)
{
  __shared__ int   sOff[64];
  __shared__ float sW[64][8];
  __shared__ float sPx[64], sPy[64], sPz[64], sVx[64], sVy[64], sVz[64];
  __shared__ ushort_t zf[64*136];
  __shared__ ushort_t Wb[64*136];    // xin (pitch 72), then recycled activation buffer

  int tid = threadIdx.x;
  int qbase = blockIdx.x * 64;

  if (tid < 64) {
    int q = qbase + tid;
    int ray = q >> RAY_SHIFT;
    float t;
    if constexpr (OUTD == 2) t = ((float)(q & 3) + 0.5f) * 25.f;
    else                     t = dvals[q];
    float ux = unit[3*ray], uy = unit[3*ray+1], uz = unit[3*ray+2];
    float wx=ux*t, wy=uy*t, wz=uz*t;
    float px = Tsi[0]*wx + Tsi[1]*wy + Tsi[2]*wz + Tsi[3];
    float py = Tsi[4]*wx + Tsi[5]*wy + Tsi[6]*wz + Tsi[7];
    float pz = Tsi[8]*wx + Tsi[9]*wy + Tsi[10]*wz + Tsi[11];
    sPx[tid]=px; sPy[tid]=py; sPz[tid]=pz;
    sVx[tid]=viewdir[3*ray]; sVy[tid]=viewdir[3*ray+1]; sVz[tid]=viewdir[3*ray+2];
    float gx = (px + 25.6f)*2.5f;
    float gy = (py + 25.6f)*2.5f;
    float gz = (pz + 2.0f)*2.5f;
    bool inb = (gx>=0.f)&&(gx<=127.f)&&(gy>=0.f)&&(gy<=127.f)&&(gz>=0.f)&&(gz<=15.f);
    gx = fminf(fmaxf(gx,0.f),127.f);
    gy = fminf(fmaxf(gy,0.f),127.f);
    gz = fminf(fmaxf(gz,0.f),15.f);
    int x0 = min(max((int)floorf(gx),0),126);
    int y0 = min(max((int)floorf(gy),0),126);
    int z0 = min(max((int)floorf(gz),0),14);
    float fx = gx-(float)x0, fy = gy-(float)y0, fz = gz-(float)z0;
    float sc = inb ? 1.f : 0.f;
    float ax0 = 1.f-fx, ay0 = 1.f-fy;
    float az0 = (1.f-fz)*sc, az1 = fz*sc;
    float q00 = ax0*ay0, q01 = ax0*fy, q10 = fx*ay0, q11 = fx*fy;
    sW[tid][0] = az0*q00; sW[tid][1] = az0*q01; sW[tid][2] = az0*q10; sW[tid][3] = az0*q11;
    sW[tid][4] = az1*q00; sW[tid][5] = az1*q01; sW[tid][6] = az1*q10; sW[tid][7] = az1*q11;
    sOff[tid] = mode ? (((z0*128 + x0)*128 + y0)*128)
                     : (z0*2097152 + x0*128 + y0);
  }
  __syncthreads();

  // trilinear gather -> zf (bf16), 8 channels per thread-iter, dwordx4 corner loads
  for (int it = 0; it < 4; ++it) {
    int lin = it*256 + tid;           // 0..1023 = 64 pts * 16 chan-blocks
    int p = lin >> 4, cb = lin & 15;
    float4 wA = *(const float4*)&sW[p][0];
    float4 wB = *(const float4*)&sW[p][4];
    float r0=0,r1=0,r2=0,r3=0,r4=0,r5=0,r6=0,r7=0;
    if (mode) {
      const ushort_t* b = vfh + sOff[p] + cb*8;
      uint4 v;
      #define ACC8(PTR, W) \
        v = *(const uint4*)(PTR); \
        r0 += (W)*b2f_lo(v.x); r1 += (W)*b2f_hi(v.x); \
        r2 += (W)*b2f_lo(v.y); r3 += (W)*b2f_hi(v.y); \
        r4 += (W)*b2f_lo(v.z); r5 += (W)*b2f_hi(v.z); \
        r6 += (W)*b2f_lo(v.w); r7 += (W)*b2f_hi(v.w);
      ACC8(b,                     wA.x)
      ACC8(b + 128,               wA.y)
      ACC8(b + 16384,             wA.z)
      ACC8(b + 16384 + 128,       wA.w)
      ACC8(b + 2097152,           wB.x)
      ACC8(b + 2097152 + 128,     wB.y)
      ACC8(b + 2097152 + 16384,   wB.z)
      ACC8(b + 2097152 + 16512,   wB.w)
      #undef ACC8
    } else {
      const float* bsrc = vf0 + sOff[p];
      float rr[8];
      #pragma unroll
      for (int k = 0; k < 8; ++k) {
        const float* bc = bsrc + (size_t)(cb*8 + k)*16384;
        rr[k] = wA.x*bc[0] + wA.y*bc[1] + wA.z*bc[128] + wA.w*bc[129]
              + wB.x*bc[2097152] + wB.y*bc[2097153] + wB.z*bc[2097280] + wB.w*bc[2097281];
      }
      r0=rr[0]; r1=rr[1]; r2=rr[2]; r3=rr[3]; r4=rr[4]; r5=rr[5]; r6=rr[6]; r7=rr[7];
    }
    uint4 o;
    o.x = pack_trunc(r0, r1); o.y = pack_trunc(r2, r3);
    o.z = pack_trunc(r4, r5); o.w = pack_trunc(r6, r7);
    *(uint4*)(zf + p*136 + cb*8) = o;
  }

  // PE inputs -> Wb as xin (pitch 72), dims 42..63 zero
  for (int it = 0; it < 16; ++it) {
    int lin = it*256 + tid;
    int p = lin >> 6, d = lin & 63;
    float val = 0.f;
    if (d < 3)      val = (d==0)?sPx[p]:((d==1)?sPy[p]:sPz[p]);
    else if (d < 39) {
      int s = d - 3; bool isSin = (s < 18); if (!isSin) s -= 18;
      int axis = s/6, fi = s%6;
      float base = (axis==0)?sPx[p]:((axis==1)?sPy[p]:sPz[p]);
      float arg = base * (float)(1 << fi);
      val = isSin ? __sinf(arg) : __cosf(arg);
    } else if (d < 42) {
      val = (d==39)?sVx[p]:((d==40)?sVy[p]:sVz[p]);
    }
    Wb[p*72 + d] = f2b_fast(val);
  }
  __syncthreads();

  int wave = tid >> 6, lane = tid & 63;
  int l15 = lane & 15, quad = lane >> 4;
  int cbase = wave*32 + quad*4;        // channel base for ct=0 (ct=1 adds 16)

  f32x4 h[2][4];
  {
    f32x4 bi0 = *(const f32x4*)(b_in + cbase);
    f32x4 bi1 = *(const f32x4*)(b_in + cbase + 16);
    #pragma unroll
    for (int nt = 0; nt < 4; ++nt) { h[0][nt] = bi0; h[1][nt] = bi1; }
  }
  gemm_accT<2>(Wb, 72, pk, h, wave, lane);

  const ushort_t* pkl = pk + 2*4096;
  #pragma unroll 1
  for (int i = 0; i < 3; ++i) {
    gemm_accT<4>(zf, 136, pkl + (size_t)(i*12)*4096, h, wave, lane);
    {
      f32x4 bz0 = *(const f32x4*)(bzv + i*128 + cbase);
      f32x4 bz1 = *(const f32x4*)(bzv + i*128 + cbase + 16);
      #pragma unroll
      for (int nt = 0; nt < 4; ++nt) { h[0][nt] += bz0; h[1][nt] += bz1; }
    }
    __syncthreads();
    store_reluT(Wb, h, wave, lane);
    __syncthreads();
    f32x4 net[2][4];
    {
      f32x4 c0b = *(const f32x4*)(b0v + i*128 + cbase);
      f32x4 c1b = *(const f32x4*)(b0v + i*128 + cbase + 16);
      #pragma unroll
      for (int nt = 0; nt < 4; ++nt) { net[0][nt] = c0b; net[1][nt] = c1b; }
    }
    gemm_accT<4>(Wb, 136, pkl + (size_t)(i*12+4)*4096, net, wave, lane);
    __syncthreads();
    store_reluT(Wb, net, wave, lane);
    __syncthreads();
    gemm_accT<4>(Wb, 136, pkl + (size_t)(i*12+8)*4096, h, wave, lane);
    {
      f32x4 o0b = *(const f32x4*)(b1v + i*128 + cbase);
      f32x4 o1b = *(const f32x4*)(b1v + i*128 + cbase + 16);
      #pragma unroll
      for (int nt = 0; nt < 4; ++nt) { h[0][nt] += o0b; h[1][nt] += o1b; }
    }
  }
  __syncthreads();
  store_reluT(Wb, h, wave, lane);
  __syncthreads();

  // epilogue: one 16x16 MFMA tile per wave; D rows = out-dims, cols = the wave's 16 points
  {
    const ushort_t* pkw = pk + 38*4096;
    f32x4 oa = (f32x4){0.f,0.f,0.f,0.f};
    #pragma unroll
    for (int ks = 0; ks < 4; ++ks) {
      short8 w = *(const short8*)(pkw + (size_t)(ks*64 + lane)*8);
      short8 b = *(const short8*)(Wb + (wave*16 + l15)*136 + ks*32 + quad*8);
      oa = __builtin_amdgcn_mfma_f32_16x16x32_bf16(w, b, oa, 0,0,0);
    }
    if (quad == 0) {
      int q = qbase + wave*16 + l15;
      if constexpr (OUTD == 4) {
        float4 o = { oa[0] + b_out[0], oa[1] + b_out[1], oa[2] + b_out[2], oa[3] + b_out[3] };
        *(float4*)(outbuf + (size_t)q*4) = o;
      } else {
        int g = q & 3;
        means[q] = fminf(fmaxf(((float)g + 0.5f)*25.f + oa[0] + b_out[0], 0.5f), 100.f);
        stds[q]  = 2.5f*sigmoid_(oa[1] + b_out[1]) + 0.1f;
      }
    }
  }
}

// ---------- per-ray depth set: build + rank-sort 64 values ----------
__global__ void k_sortd(const float* __restrict__ means, const float* __restrict__ stds,
                        const float* __restrict__ noise, float* __restrict__ dsort, int R){
  __shared__ float buf[4][64];
  int lr = threadIdx.x >> 6, p = threadIdx.x & 63;
  int ray = blockIdx.x*4 + lr;
  float val;
  if (p < 32) val = 0.5f + (float)p * (99.5f/31.f);
  else {
    int idx = p - 32, g = idx >> 3, s = idx & 7;
    float mu = means[ray*4+g], sd = stds[ray*4+g];
    val = fminf(fmaxf(mu + sd*noise[(ray*4+g)*8 + s], 0.5f), 100.f);
  }
  buf[lr][p] = val;
  __syncthreads();
  int rank = 0;
  for (int k = 0; k < 64; ++k) {
    float o = buf[lr][k];
    rank += (o < val) || (o == val && k < p);
  }
  dsort[ray*64 + rank] = val;
}

// ---------- render + losses: one wave per ray, lane = sample ----------
__device__ __forceinline__ void bilin3(const float* __restrict__ img, float u, float v, float* out){
  u = fminf(fmaxf(u, 0.f), (float)(WIMG-1));
  v = fminf(fmaxf(v, 0.f), (float)(HIMG-1));
  int u0 = min(max((int)floorf(u),0), WIMG-2);
  int v0 = min(max((int)floorf(v),0), HIMG-2);
  float fu = u - (float)u0, fv = v - (float)v0;
  float w00=(1.f-fv)*(1.f-fu), w01=(1.f-fv)*fu, w10=fv*(1.f-fu), w11=fv*fu;
  #pragma unroll
  for (int c = 0; c < 3; ++c) {
    const float* b = img + (size_t)c*(HIMG*WIMG) + (size_t)v0*WIMG + u0;
    out[c] = w00*b[0] + w01*b[1] + w10*b[WIMG] + w11*b[WIMG+1];
  }
}

__global__ void k_render(const float* __restrict__ outbuf, const float* __restrict__ dsort,
                         const float* __restrict__ means, const float* __restrict__ stds,
                         const float* __restrict__ unit,
                         const float* __restrict__ img_src, const float* __restrict__ img_tgt,
                         const int* __restrict__ pix, const float* __restrict__ camK,
                         const float* __restrict__ Tst, float* __restrict__ rayloss, int R){
  int gid = blockIdx.x*blockDim.x + threadIdx.x;
  int r = gid >> 6, lane = gid & 63;
  if (r >= R) return;
  float d = dsort[(size_t)r*64 + lane];
  float dn = __shfl_down(d, 1);
  float delta = (lane < 63) ? (dn - d) : 1e10f;
  float4 o = *(const float4*)(outbuf + (size_t)r*256 + lane*4);
  float sig = softplus_(o.x);
  float alpha = 1.f - __expf(-sig*delta);
  float om = 1.f - alpha + 1e-10f;
  float prod = om;
  #pragma unroll
  for (int off = 1; off < 64; off <<= 1) {
    float v = __shfl_up(prod, off);
    if (lane >= off) prod *= v;
  }
  float texc = __shfl_up(prod, 1);
  if (lane == 0) texc = 1.f;
  float w = alpha * texc;
  float m0=means[r*4],m1=means[r*4+1],m2=means[r*4+2],m3=means[r*4+3];
  float s0=stds[r*4], s1=stds[r*4+1], s2=stds[r*4+2], s3=stds[r*4+3];
  float t0=(d-m0)/s0, t1=(d-m1)/s1, t2=(d-m2)/s2, t3=(d-m3)/s3;
  float pm = 0.25f*0.3989422804014327f*(__expf(-0.5f*t0*t0)/s0 + __expf(-0.5f*t1*t1)/s1
                                      + __expf(-0.5f*t2*t2)/s2 + __expf(-0.5f*t3*t3)/s3);
  float kl  = w * (-__logf(pm + 1e-6f));
  float dep = w * d;
  float c0 = w * sigmoid_(o.y);
  float c1 = w * sigmoid_(o.z);
  float c2 = w * sigmoid_(o.w);
  #pragma unroll
  for (int off = 32; off; off >>= 1) {
    dep += __shfl_xor(dep, off);
    c0  += __shfl_xor(c0, off);
    c1  += __shfl_xor(c1, off);
    c2  += __shfl_xor(c2, off);
    kl  += __shfl_xor(kl, off);
  }
  if (lane == 0) {
    float ld = fminf(fminf(fabsf(m0-dep),fabsf(m1-dep)), fminf(fabsf(m2-dep),fabsf(m3-dep)));
    float src[3], tgt[3];
    float u = (float)pix[2*r], v = (float)pix[2*r+1];
    bilin3(img_src, u, v, src);
    float ux=unit[3*r],uy=unit[3*r+1],uz=unit[3*r+2];
    float pcx=ux*dep, pcy=uy*dep, pcz=uz*dep;
    float ptx = Tst[0]*pcx + Tst[1]*pcy + Tst[2]*pcz + Tst[3];
    float pty = Tst[4]*pcx + Tst[5]*pcy + Tst[6]*pcz + Tst[7];
    float ptz = Tst[8]*pcx + Tst[9]*pcy + Tst[10]*pcz + Tst[11];
    float prx = camK[0]*ptx + camK[1]*pty + camK[2]*ptz;
    float pry = camK[3]*ptx + camK[4]*pty + camK[5]*ptz;
    float prz = camK[6]*ptx + camK[7]*pty + camK[8]*ptz;
    prz = fmaxf(prz, 0.001f);
    bilin3(img_tgt, prx/prz, pry/prz, tgt);
    float lrepr = fabsf(src[0]-tgt[0])+fabsf(src[1]-tgt[1])+fabsf(src[2]-tgt[2]);
    float lcol  = fabsf(src[0]-c0)+fabsf(src[1]-c1)+fabsf(src[2]-c2);
    float invR = 1.f/(float)R;
    rayloss[r] = (lrepr + lcol) * (invR/3.f) + kl*invR + 0.01f*ld*invR;
  }
}

__global__ void k_reduce(const float* __restrict__ rayloss, float* __restrict__ out, int R){
  __shared__ float sm[256];
  float acc = 0.f;
  for (int i = threadIdx.x; i < R; i += 256) acc += rayloss[i];
  sm[threadIdx.x] = acc;
  __syncthreads();
  for (int s = 128; s > 0; s >>= 1) {
    if ((int)threadIdx.x < s) sm[threadIdx.x] += sm[threadIdx.x + s];
    __syncthreads();
  }
  if (threadIdx.x == 0) out[0] = sm[0];
}

extern "C" void kernel_launch(void* const* d_in, const int* in_sizes, int n_in,
                              void* d_out, int out_size, void* d_ws, size_t ws_size,
                              hipStream_t stream)
{
  const float* bev   = (const float*)d_in[0];
  const float* camK  = (const float*)d_in[1];
  const float* img_s = (const float*)d_in[2];
  const float* img_t = (const float*)d_in[3];
  const float* Tsi   = (const float*)d_in[4];
  const float* Tst   = (const float*)d_in[5];
  const float* noise = (const float*)d_in[6];
  const int*   pix   = (const int*)d_in[7];
  const float* m_w_in=(const float*)d_in[8];  const float* m_b_in=(const float*)d_in[9];
  const float* m_wz  =(const float*)d_in[10]; const float* m_bz  =(const float*)d_in[11];
  const float* m_w0  =(const float*)d_in[12]; const float* m_b0  =(const float*)d_in[13];
  const float* m_w1  =(const float*)d_in[14]; const float* m_b1  =(const float*)d_in[15];
  const float* m_wo  =(const float*)d_in[16]; const float* m_bo  =(const float*)d_in[17];
  const float* g_w_in=(const float*)d_in[18]; const float* g_b_in=(const float*)d_in[19];
  const float* g_wz  =(const float*)d_in[20]; const float* g_bz  =(const float*)d_in[21];
  const float* g_w0  =(const float*)d_in[22]; const float* g_b0  =(const float*)d_in[23];
  const float* g_w1  =(const float*)d_in[24]; const float* g_b1  =(const float*)d_in[25];
  const float* g_wo  =(const float*)d_in[26]; const float* g_bo  =(const float*)d_in[27];

  int R = in_sizes[7] / 2;
  float* ws = (float*)d_ws;
  size_t off = 0;
  float* unitb = ws + off; off += (size_t)R*3;
  float* vdirb = ws + off; off += (size_t)R*3;
  float* means = ws + off; off += (size_t)R*4;
  float* stds  = ws + off; off += (size_t)R*4;
  float* dsort = ws + off; off += (size_t)R*64;
  float* outbf = ws + off; off += (size_t)R*256;
  float* rlos  = ws + off; off += (size_t)R;
  ushort_t* pkM = (ushort_t*)(ws + off);
  ushort_t* pkG = pkM + 39*4096;
  off += 39*4096 + 64;
  off = (off + 63) & ~(size_t)63;
  ushort_t* vfh = (ushort_t*)(ws + off);
  size_t need = off*4ull + (size_t)16*128*128*128*2ull;
  int mode = (ws_size >= need) ? 1 : 0;

  k_pack<<<624,256,0,stream>>>(m_w_in, m_wz, m_w0, m_w1, m_wo, 4, pkM);
  k_pack<<<624,256,0,stream>>>(g_w_in, g_wz, g_w0, g_w1, g_wo, 2, pkG);
  if (mode) {
    dim3 g(4,4,2048), b(32,8);
    k_transpose<<<g,b,0,stream>>>(bev, vfh);
  }
  k_rayinit<<<(R+255)/256,256,0,stream>>>(camK,pix,Tsi,unitb,vdirb,R);
  k_fused<2,2><<<R/16,256,0,stream>>>(vfh,bev,mode,unitb,vdirb,Tsi,nullptr,pkG,
      g_b_in,g_bz,g_b0,g_b1,g_bo, means,stds,nullptr);
  k_sortd<<<R/4,256,0,stream>>>(means,stds,noise,dsort,R);
  k_fused<4,6><<<R,256,0,stream>>>(vfh,bev,mode,unitb,vdirb,Tsi,dsort,pkM,
      m_b_in,m_bz,m_b0,m_b1,m_bo, nullptr,nullptr,outbf);
  k_render<<<R/4,256,0,stream>>>(outbf,dsort,means,stds,unitb,img_s,img_t,pix,camK,Tst,rlos,R);
  k_reduce<<<1,256,0,stream>>>(rlos,(float*)d_out,R);
}